// Round 7
// baseline (2502.061 us; speedup 1.0000x reference)
//
#include <hip/hip_runtime.h>
#include <math.h>

#define B_ 4
#define C_ 128
#define HW_ 65536
#define H__ 256
#define KF_ 129
#define PLANEF_ 33024

typedef __attribute__((ext_vector_type(8))) short short8v;
typedef __attribute__((ext_vector_type(4))) float f32x4;

__device__ __forceinline__ unsigned short f2bf(float f) {
    union { float f; unsigned u; } v; v.f = f;
    return (unsigned short)((v.u + 0x7FFFu + ((v.u >> 16) & 1u)) >> 16);
}
__device__ __forceinline__ float bf2f(unsigned short s) {
    union { unsigned u; float f; } v; v.u = (unsigned)s << 16;
    return v.f;
}
// fast gelu: A&S 7.1.26 erf (|err|<=1.5e-7) with __expf
__device__ __forceinline__ float geluf(float x) {
    float z = 0.70710678118654752f * fabsf(x);
    float t = __fdividef(1.f, fmaf(0.3275911f, z, 1.f));
    float p = fmaf(1.061405429f, t, -1.453152027f);
    p = fmaf(p, t, 1.421413741f);
    p = fmaf(p, t, -0.284496736f);
    p = fmaf(p, t, 0.254829592f);
    p = p * t;
    float erfv = 1.f - p * __expf(-z * z);
    float cdf = (x >= 0.f) ? fmaf(0.5f, erfv, 0.5f) : fmaf(-0.5f, erfv, 0.5f);
    return x * cdf;
}
// fast atan2, poly err ~1e-5 rad (far below bf16 staging precision)
__device__ __forceinline__ float fatan2(float y, float x) {
    float ax = fabsf(x), ay = fabsf(y);
    float mx = fmaxf(ax, ay), mn = fminf(ax, ay);
    float a = __fdividef(mn, fmaxf(mx, 1e-38f));
    float s = a * a;
    float r = fmaf(0.0208351f, s, -0.0851330f);
    r = fmaf(r, s, 0.1801410f);
    r = fmaf(r, s, -0.3302995f);
    r = fmaf(r, s, 0.9998660f);
    r = r * a;
    if (ay > ax) r = 1.57079632679489662f - r;
    if (x < 0.f) r = 3.14159265358979324f - r;
    return copysignf(r, y);
}
// LDS XOR swizzle: flip 16B-slot bits of byte-offset-in-row with (px>>2)&7
template<int W>
__device__ __forceinline__ char* swz_ptr(unsigned short (*xs)[W], int px, int cb) {
    return (char*)xs + px * (W * 2) + (cb ^ (((px >> 2) & 7) << 4));
}

// ---------------------------------------------------------------- prep
__global__ __launch_bounds__(256) void tobf16_kernel(const float* __restrict__ src,
                                                     unsigned short* __restrict__ dst, int n)
{
    int i = blockIdx.x * 256 + threadIdx.x;
    if (i < n) dst[i] = f2bf(src[i]);
}

__global__ __launch_bounds__(128) void foldln_kernel(const float* __restrict__ W,
                                                     const float* __restrict__ lnw,
                                                     const float* __restrict__ lnb,
                                                     unsigned short* __restrict__ Wb,
                                                     float* __restrict__ wsum, float* __restrict__ bsum,
                                                     int Cc)
{
    int o = blockIdx.x, t = threadIdx.x;
    float sw = 0.f, sb = 0.f;
    for (int c = t; c < Cc; c += 128) {
        float w = W[(size_t)o * Cc + c];
        float fw = w * lnw[c];
        unsigned short us = f2bf(fw);
        Wb[(size_t)o * Cc + c] = us;
        sw += bf2f(us);
        sb += w * lnb[c];
    }
    __shared__ float r1[128], r2[128];
    r1[t] = sw; r2[t] = sb; __syncthreads();
    for (int st = 64; st; st >>= 1) {
        if (t < st) { r1[t] += r1[t + st]; r2[t] += r2[t + st]; }
        __syncthreads();
    }
    if (!t) { wsum[o] = r1[0]; bsum[o] = r2[0]; }
}

__global__ __launch_bounds__(256) void poutperm_kernel(const float* __restrict__ src,
                                                       unsigned short* __restrict__ dst)
{
    int i = blockIdx.x * 256 + threadIdx.x;   // 32768
    int half = i >> 14, rem = i & 16383, o = rem >> 7, kp = rem & 127;
    int h = (kp >> 5) * 64 + half * 32 + (kp & 31);
    dst[i] = f2bf(src[o * 256 + h]);
}

__global__ void pinc_kernel(const float* __restrict__ bb, const float* __restrict__ ws,
                            float4* __restrict__ pinC)
{
    int i = threadIdx.x;
    if (i < 256) pinC[i] = make_float4(bb[i], ws[i], bb[i + 256], ws[i + 256]);
}

__global__ void ksum_kernel(const float* __restrict__ dw, float* __restrict__ ks)
{
    int c = threadIdx.x;
    if (c < C_) {
        float s = 0.f;
        for (int k = 0; k < 9; ++k) s += dw[c * 9 + k];
        ks[c] = s;
    }
}

__global__ __launch_bounds__(256) void zero2_kernel(float* __restrict__ a, float* __restrict__ b, int n)
{
    int i = blockIdx.x * 256 + threadIdx.x;
    if (i < n) { a[i] = 0.f; b[i] = 0.f; }
}

// ---------------------------------------------------------------- MFMA conv1x1 (CIN=128)
// PRO==1: leaky(0.1) on staged value. LNF: register LN stats + folded-affine epilogue.
// flags&1: +1e-8 after bias.
template<int PRO, bool LNF>
__global__ __launch_bounds__(256, 3) void mconv2(
    const float* __restrict__ X, size_t sx,
    const unsigned short* __restrict__ Wb, int wstride,
    const float* __restrict__ bias,
    const float* __restrict__ res, size_t sres,
    float* __restrict__ Y, size_t sy, int plane, int flags,
    const float* __restrict__ wsum, const float* __restrict__ bsum)
{
    __shared__ unsigned short xs[128][136];
    __shared__ float2 lnred[LNF ? 8 : 1][LNF ? 128 : 1];
    __shared__ float2 lnmi[LNF ? 128 : 1];
    const int t = threadIdx.x;
    const int bz = blockIdx.z;
    const int p0 = blockIdx.x * 128;
    const int lane = t & 63;
    const int wr = t >> 7, wc = (t >> 6) & 1;
    const int lr = lane >> 4, lc = lane & 15;
    const float* Xb = X + (size_t)bz * sx;
    const int px4 = t & 31;

    float s0 = 0.f, s1 = 0.f, s2v = 0.f, s3 = 0.f;
    float q0 = 0.f, q1 = 0.f, q2 = 0.f, q3 = 0.f;

#pragma unroll
    for (int g = 0; g < 2; ++g) {
        float4 st[8];
#pragma unroll
        for (int i = 0; i < 8; ++i) {
            int e = t + (g * 8 + i) * 256;           // 4096 items: 128c x 32 px4
            int c = e >> 5;
            st[i] = *(const float4*)(Xb + (size_t)c * plane + p0 + px4 * 4);
        }
#pragma unroll
        for (int i = 0; i < 8; ++i) {
            int e = t + (g * 8 + i) * 256;
            int c = e >> 5;
            float a0 = st[i].x, a1 = st[i].y, a2 = st[i].z, a3 = st[i].w;
            if constexpr (PRO == 1) {
                a0 = a0 > 0.f ? a0 : 0.1f * a0;
                a1 = a1 > 0.f ? a1 : 0.1f * a1;
                a2 = a2 > 0.f ? a2 : 0.1f * a2;
                a3 = a3 > 0.f ? a3 : 0.1f * a3;
            }
            if constexpr (LNF) {
                s0 += a0; q0 += a0 * a0;
                s1 += a1; q1 += a1 * a1;
                s2v += a2; q2 += a2 * a2;
                s3 += a3; q3 += a3 * a3;
            }
            *(unsigned short*)swz_ptr(xs, px4 * 4 + 0, 2 * c) = f2bf(a0);
            *(unsigned short*)swz_ptr(xs, px4 * 4 + 1, 2 * c) = f2bf(a1);
            *(unsigned short*)swz_ptr(xs, px4 * 4 + 2, 2 * c) = f2bf(a2);
            *(unsigned short*)swz_ptr(xs, px4 * 4 + 3, 2 * c) = f2bf(a3);
        }
    }
    if constexpr (LNF) {
        lnred[t >> 5][px4 * 4 + 0] = make_float2(s0, q0);
        lnred[t >> 5][px4 * 4 + 1] = make_float2(s1, q1);
        lnred[t >> 5][px4 * 4 + 2] = make_float2(s2v, q2);
        lnred[t >> 5][px4 * 4 + 3] = make_float2(s3, q3);
    }
    __syncthreads();
    if constexpr (LNF) {
        if (t < 128) {
            float ss = 0.f, qq = 0.f;
#pragma unroll
            for (int j = 0; j < 8; ++j) { float2 a = lnred[j][t]; ss += a.x; qq += a.y; }
            float m = ss * (1.f / 128.f);
            float inv = rsqrtf(qq * (1.f / 128.f) - m * m + 1e-5f);
            lnmi[t] = make_float2(m, inv);
        }
        __syncthreads();
    }

    f32x4 acc[4][4];
#pragma unroll
    for (int mi = 0; mi < 4; ++mi)
#pragma unroll
        for (int ni = 0; ni < 4; ++ni) acc[mi][ni] = (f32x4){0.f, 0.f, 0.f, 0.f};

#pragma unroll
    for (int kk = 0; kk < 128; kk += 32) {
        short8v bfr[4];
#pragma unroll
        for (int ni = 0; ni < 4; ++ni)
            bfr[ni] = *(const short8v*)swz_ptr(xs, wc * 64 + ni * 16 + lc, 2 * (kk + lr * 8));
#pragma unroll
        for (int mi = 0; mi < 4; ++mi) {
            int row = wr * 64 + mi * 16 + lc;
            short8v afr = *(const short8v*)(Wb + (size_t)row * wstride + kk + lr * 8);
#pragma unroll
            for (int ni = 0; ni < 4; ++ni)
                acc[mi][ni] = __builtin_amdgcn_mfma_f32_16x16x32_bf16(afr, bfr[ni], acc[mi][ni], 0, 0, 0);
        }
    }

    float2 mrow[4];
    if constexpr (LNF) {
#pragma unroll
        for (int ni = 0; ni < 4; ++ni) mrow[ni] = lnmi[wc * 64 + ni * 16 + lc];
    }

#pragma unroll
    for (int mi = 0; mi < 4; ++mi) {
        int ob = wr * 64 + mi * 16 + lr * 4;
#pragma unroll
        for (int r = 0; r < 4; ++r) {
            int o = ob + r;
            float bv = 0.f, wso = 0.f;
            if constexpr (LNF) { bv = bsum[o]; wso = wsum[o]; }
            else { if (bias) bv = bias[o]; if (flags & 1) bv += 1e-8f; }
#pragma unroll
            for (int ni = 0; ni < 4; ++ni) {
                int px = wc * 64 + ni * 16 + lc;
                float v;
                if constexpr (LNF) {
                    float m = mrow[ni].x, inv = mrow[ni].y;
                    v = acc[mi][ni][r] * inv + bv - m * inv * wso;
                } else {
                    v = acc[mi][ni][r] + bv;
                }
                size_t yi = (size_t)bz * sy + (size_t)o * plane + p0 + px;
                if (res) v += res[(size_t)bz * sres + (size_t)o * plane + p0 + px];
                Y[yi] = v;
            }
        }
    }
}

// ---------------------------------------------------------------- fused amp1+pha1 spectral conv (CIN=256 over two spectra)
// LDS: 128-px rows x 64-ch chunk (+pad) per tensor  [round-6 bug: rows were 64]
__global__ __launch_bounds__(256, 2) void apconv(
    const float2* __restrict__ T1, const float2* __restrict__ T2, size_t sT,
    const unsigned short* __restrict__ Wa, const unsigned short* __restrict__ Wp,
    const float* __restrict__ ba, const float* __restrict__ bp,
    float* __restrict__ AH, float* __restrict__ PH, size_t sO)
{
    __shared__ unsigned short xa[128][72];
    __shared__ unsigned short xp[128][72];
    const int t = threadIdx.x;
    const int bz = blockIdx.z;
    const int p0 = blockIdx.x * 128;
    const int lane = t & 63;
    const int wr = t >> 7, wc = (t >> 6) & 1;
    const int lr = lane >> 4, lc = lane & 15;
    const int px2 = t & 63;

    f32x4 aa[4][4], ap[4][4];
#pragma unroll
    for (int mi = 0; mi < 4; ++mi)
#pragma unroll
        for (int ni = 0; ni < 4; ++ni) { aa[mi][ni] = (f32x4){0.f,0.f,0.f,0.f}; ap[mi][ni] = (f32x4){0.f,0.f,0.f,0.f}; }

    for (int ch = 0; ch < 256; ch += 64) {
        const float2* Ts = ((ch < 128) ? T1 : T2) + (size_t)bz * sT + (size_t)(ch & 127) * PLANEF_;
#pragma unroll
        for (int g = 0; g < 2; ++g) {
            float4 st[8];
#pragma unroll
            for (int i = 0; i < 8; ++i) {
                int e = t + (g * 8 + i) * 256;       // 4096 items: 64c x 64 px2 (=128 px)
                int c = e >> 6;
                st[i] = *(const float4*)(Ts + (size_t)c * PLANEF_ + p0 + px2 * 2);
            }
#pragma unroll
            for (int i = 0; i < 8; ++i) {
                int e = t + (g * 8 + i) * 256;
                int c = e >> 6;
                float m0 = sqrtf(st[i].x * st[i].x + st[i].y * st[i].y);
                float m1 = sqrtf(st[i].z * st[i].z + st[i].w * st[i].w);
                float a0 = fatan2(st[i].y, st[i].x);
                float a1 = fatan2(st[i].w, st[i].z);
                *(unsigned short*)swz_ptr(xa, px2 * 2 + 0, 2 * c) = f2bf(m0);
                *(unsigned short*)swz_ptr(xa, px2 * 2 + 1, 2 * c) = f2bf(m1);
                *(unsigned short*)swz_ptr(xp, px2 * 2 + 0, 2 * c) = f2bf(a0);
                *(unsigned short*)swz_ptr(xp, px2 * 2 + 1, 2 * c) = f2bf(a1);
            }
        }
        __syncthreads();
#pragma unroll
        for (int kk = 0; kk < 64; kk += 32) {
            short8v bfa[4], bfp[4];
#pragma unroll
            for (int ni = 0; ni < 4; ++ni) {
                bfa[ni] = *(const short8v*)swz_ptr(xa, wc * 64 + ni * 16 + lc, 2 * (kk + lr * 8));
                bfp[ni] = *(const short8v*)swz_ptr(xp, wc * 64 + ni * 16 + lc, 2 * (kk + lr * 8));
            }
#pragma unroll
            for (int mi = 0; mi < 4; ++mi) {
                int row = wr * 64 + mi * 16 + lc;
                short8v afa = *(const short8v*)(Wa + (size_t)row * 256 + ch + kk + lr * 8);
                short8v afp = *(const short8v*)(Wp + (size_t)row * 256 + ch + kk + lr * 8);
#pragma unroll
                for (int ni = 0; ni < 4; ++ni) {
                    aa[mi][ni] = __builtin_amdgcn_mfma_f32_16x16x32_bf16(afa, bfa[ni], aa[mi][ni], 0, 0, 0);
                    ap[mi][ni] = __builtin_amdgcn_mfma_f32_16x16x32_bf16(afp, bfp[ni], ap[mi][ni], 0, 0, 0);
                }
            }
        }
        __syncthreads();
    }

#pragma unroll
    for (int mi = 0; mi < 4; ++mi) {
        int ob = wr * 64 + mi * 16 + lr * 4;
#pragma unroll
        for (int r = 0; r < 4; ++r) {
            int o = ob + r;
            float bva = ba[o], bvp = bp[o];
#pragma unroll
            for (int ni = 0; ni < 4; ++ni) {
                int px = wc * 64 + ni * 16 + lc;
                size_t yi = (size_t)bz * sO + (size_t)o * PLANEF_ + p0 + px;
                AH[yi] = aa[mi][ni][r] + bva;
                PH[yi] = ap[mi][ni][r] + bvp;
            }
        }
    }
}

// ---------------------------------------------------------------- fused MFMA FFN
__global__ __launch_bounds__(256, 3) void ffn_mfma4(
    const float* __restrict__ x, const float* __restrict__ fre,
    const unsigned short* __restrict__ pinb,    // [512][256] folded bf16
    const unsigned short* __restrict__ pout2,   // [2][128][128] permuted bf16
    const float4* __restrict__ pinC,            // [256] (bb1,ws1,bb2,ws2)
    float* __restrict__ out)
{
    __shared__ unsigned short xs[64][264];
    __shared__ unsigned short hs[64][136];
    __shared__ float2 muinv[64];
    float2* sred = (float2*)&hs[0][0];          // overlay: dead until GEMM1 epilogue
    const int b = blockIdx.y;
    const size_t p0 = (size_t)blockIdx.x * 64;
    const int t = threadIdx.x;
    const int wave = t >> 6, lane = t & 63;
    const int lr = lane >> 4, lc = lane & 15;
    const int px4 = t & 15;

    float s0 = 0.f, s1 = 0.f, s2v = 0.f, s3 = 0.f;
    float q0 = 0.f, q1 = 0.f, q2 = 0.f, q3 = 0.f;
#pragma unroll
    for (int g = 0; g < 2; ++g) {
        float4 st[8];
#pragma unroll
        for (int i = 0; i < 8; ++i) {
            int e = t + (g * 8 + i) * 256;               // 4096 items: 256c x 16 px4
            int c = e >> 4;
            const float* src = (c < 128) ? x + ((size_t)b * 128 + c) * HW_ + p0 + px4 * 4
                                         : fre + ((size_t)b * 128 + (c - 128)) * HW_ + p0 + px4 * 4;
            st[i] = *(const float4*)src;
        }
#pragma unroll
        for (int i = 0; i < 8; ++i) {
            int e = t + (g * 8 + i) * 256;
            int c = e >> 4;
            float a0 = st[i].x, a1 = st[i].y, a2 = st[i].z, a3 = st[i].w;
            s0 += a0; q0 += a0 * a0;
            s1 += a1; q1 += a1 * a1;
            s2v += a2; q2 += a2 * a2;
            s3 += a3; q3 += a3 * a3;
            *(unsigned short*)swz_ptr(xs, px4 * 4 + 0, 2 * c) = f2bf(a0);
            *(unsigned short*)swz_ptr(xs, px4 * 4 + 1, 2 * c) = f2bf(a1);
            *(unsigned short*)swz_ptr(xs, px4 * 4 + 2, 2 * c) = f2bf(a2);
            *(unsigned short*)swz_ptr(xs, px4 * 4 + 3, 2 * c) = f2bf(a3);
        }
    }
    sred[(t >> 4) * 64 + px4 * 4 + 0] = make_float2(s0, q0);
    sred[(t >> 4) * 64 + px4 * 4 + 1] = make_float2(s1, q1);
    sred[(t >> 4) * 64 + px4 * 4 + 2] = make_float2(s2v, q2);
    sred[(t >> 4) * 64 + px4 * 4 + 3] = make_float2(s3, q3);
    __syncthreads();
    if (t < 64) {
        float ss = 0.f, qq = 0.f;
#pragma unroll
        for (int j = 0; j < 16; ++j) { float2 a = sred[j * 64 + t]; ss += a.x; qq += a.y; }
        float m = ss * (1.f / 256.f);
        float inv = rsqrtf(qq * (1.f / 256.f) - m * m + 1e-5f);
        muinv[t] = make_float2(m, inv);
    }
    __syncthreads();

    float2 mrow[4];
#pragma unroll
    for (int ni = 0; ni < 4; ++ni) mrow[ni] = muinv[ni * 16 + lc];

    f32x4 oc[2][4];
#pragma unroll
    for (int mi = 0; mi < 2; ++mi)
#pragma unroll
        for (int ni = 0; ni < 4; ++ni) oc[mi][ni] = (f32x4){0.f, 0.f, 0.f, 0.f};

#pragma unroll
    for (int half = 0; half < 2; ++half) {
        f32x4 a1[2][4], a2[2][4];
#pragma unroll
        for (int mi = 0; mi < 2; ++mi)
#pragma unroll
            for (int ni = 0; ni < 4; ++ni) { a1[mi][ni] = (f32x4){0.f,0.f,0.f,0.f}; a2[mi][ni] = (f32x4){0.f,0.f,0.f,0.f}; }

#pragma unroll
        for (int k0 = 0; k0 < 256; k0 += 32) {
            short8v bfr[4];
#pragma unroll
            for (int ni = 0; ni < 4; ++ni)
                bfr[ni] = *(const short8v*)swz_ptr(xs, ni * 16 + lc, 2 * (k0 + lr * 8));
#pragma unroll
            for (int mi = 0; mi < 2; ++mi) {
                int hrow = wave * 64 + half * 32 + mi * 16 + lc;
                short8v af1 = *(const short8v*)(pinb + (size_t)hrow * 256 + k0 + lr * 8);
                short8v af2 = *(const short8v*)(pinb + (size_t)(hrow + 256) * 256 + k0 + lr * 8);
#pragma unroll
                for (int ni = 0; ni < 4; ++ni) {
                    a1[mi][ni] = __builtin_amdgcn_mfma_f32_16x16x32_bf16(af1, bfr[ni], a1[mi][ni], 0, 0, 0);
                    a2[mi][ni] = __builtin_amdgcn_mfma_f32_16x16x32_bf16(af2, bfr[ni], a2[mi][ni], 0, 0, 0);
                }
            }
        }
        __syncthreads();   // prior-half GEMM2 readers (and round-1 sred readers) done before hs write
#pragma unroll
        for (int mi = 0; mi < 2; ++mi)
#pragma unroll
            for (int r = 0; r < 4; ++r) {
                int ho = wave * 64 + half * 32 + mi * 16 + lr * 4 + r;   // [0,256)
                float4 bwc = pinC[ho];
                int kp = wave * 32 + mi * 16 + lr * 4 + r;
#pragma unroll
                for (int ni = 0; ni < 4; ++ni) {
                    float m = mrow[ni].x, inv = mrow[ni].y;
                    float v1 = a1[mi][ni][r] * inv + bwc.x - m * inv * bwc.y;
                    float v2 = a2[mi][ni][r] * inv + bwc.z - m * inv * bwc.w;
                    hs[ni * 16 + lc][kp] = f2bf(geluf(v1) * v2);
                }
            }
        __syncthreads();
#pragma unroll
        for (int k0 = 0; k0 < 128; k0 += 32) {
            short8v bfr2[4];
#pragma unroll
            for (int ni = 0; ni < 4; ++ni)
                bfr2[ni] = *(const short8v*)&hs[ni * 16 + lc][k0 + lr * 8];
#pragma unroll
            for (int mi = 0; mi < 2; ++mi) {
                int orow = wave * 32 + mi * 16 + lc;
                short8v af = *(const short8v*)(pout2 + half * 16384 + orow * 128 + k0 + lr * 8);
#pragma unroll
                for (int ni = 0; ni < 4; ++ni)
                    oc[mi][ni] = __builtin_amdgcn_mfma_f32_16x16x32_bf16(af, bfr2[ni], oc[mi][ni], 0, 0, 0);
            }
        }
    }

#pragma unroll
    for (int mi = 0; mi < 2; ++mi)
#pragma unroll
        for (int r = 0; r < 4; ++r) {
            int o = wave * 32 + mi * 16 + lr * 4 + r;
#pragma unroll
            for (int ni = 0; ni < 4; ++ni) {
                size_t yi = ((size_t)b * 128 + o) * HW_ + p0 + ni * 16 + lc;
                out[yi] = oc[mi][ni][r] + x[yi];
            }
        }
}

// ---------------------------------------------------------------- depthwise 3x3 cd-conv + fused sum-of-squares
__global__ __launch_bounds__(256) void dwconv2(const float* __restrict__ X, size_t sx,
                                               const float* __restrict__ w9,
                                               const float* __restrict__ ksum,
                                               float* __restrict__ Y, size_t sy,
                                               float* __restrict__ ssq)
{
    int bz = blockIdx.z;
    int c = blockIdx.y;
    int p4 = blockIdx.x * 256 + threadIdx.x;
    int p0 = p4 * 4;
    int i = p0 >> 8, j0 = p0 & 255;
    const float* xp = X + (size_t)bz * sx + (size_t)c * HW_;
    const float* wc = w9 + c * 9;
    float a[4] = {0.f, 0.f, 0.f, 0.f};
#pragma unroll
    for (int di = -1; di <= 1; ++di) {
        int ii = i + di;
        if (ii < 0 || ii > 255) continue;
        const float* row = xp + ii * 256;
        float4 m4 = *(const float4*)(row + j0);
        float lft = (j0 > 0) ? row[j0 - 1] : 0.f;
        float rgt = (j0 < 252) ? row[j0 + 4] : 0.f;
        float v[6] = {lft, m4.x, m4.y, m4.z, m4.w, rgt};
        float w0 = wc[(di + 1) * 3], w1 = wc[(di + 1) * 3 + 1], w2 = wc[(di + 1) * 3 + 2];
#pragma unroll
        for (int k = 0; k < 4; ++k) a[k] += w0 * v[k] + w1 * v[k + 1] + w2 * v[k + 2];
    }
    float4 ctr = *(const float4*)(xp + i * 256 + j0);
    float km = 0.7f * ksum[c];
    float4 o;
    o.x = a[0] - km * ctr.x; o.y = a[1] - km * ctr.y;
    o.z = a[2] - km * ctr.z; o.w = a[3] - km * ctr.w;
    *(float4*)(Y + (size_t)bz * sy + (size_t)c * HW_ + p0) = o;

    float q = o.x * o.x + o.y * o.y + o.z * o.z + o.w * o.w;
    __shared__ float red[256];
    red[threadIdx.x] = q; __syncthreads();
    for (int st = 128; st; st >>= 1) {
        if (threadIdx.x < st) red[threadIdx.x] += red[threadIdx.x + st];
        __syncthreads();
    }
    if (!threadIdx.x) atomicAdd(&ssq[bz * C_ + c], red[0]);
}

// ---------------------------------------------------------------- attention helpers (batched)
__global__ __launch_bounds__(256) void gram_kernel(const float* __restrict__ Q, size_t sq,
                                                   const float* __restrict__ K, size_t sk,
                                                   float* __restrict__ part)
{
    int sl = blockIdx.x, h = blockIdx.y, bz = blockIdx.z;
    const float* qb = Q + (size_t)bz * sq + (size_t)(h * 16) * HW_;
    const float* kb = K + (size_t)bz * sk + (size_t)(h * 16) * HW_;
    __shared__ __align__(16) float qs[16][68];
    __shared__ __align__(16) float ks[16][68];
    int c = threadIdx.x >> 4, d = threadIdx.x & 15;
    float acc = 0.f;
    for (int n0 = sl * 2048; n0 < (sl + 1) * 2048; n0 += 64) {
        for (int e = threadIdx.x; e < 1024; e += 256) {
            int cc = e >> 6, nn = e & 63;
            qs[cc][nn] = qb[(size_t)cc * HW_ + n0 + nn];
            ks[cc][nn] = kb[(size_t)cc * HW_ + n0 + nn];
        }
        __syncthreads();
#pragma unroll
        for (int nn = 0; nn < 64; nn += 4) {
            float4 qv = *(const float4*)&qs[c][nn];
            float4 kv = *(const float4*)&ks[d][nn];
            acc += qv.x * kv.x + qv.y * kv.y + qv.z * kv.z + qv.w * kv.w;
        }
        __syncthreads();
    }
    part[((size_t)(bz * 8 + h) * 32 + sl) * 256 + threadIdx.x] = acc;
}

__global__ __launch_bounds__(256) void softmax_kernel(const float* __restrict__ part,
                                                      const float* __restrict__ nqsq,
                                                      const float* __restrict__ nksq,
                                                      const float* __restrict__ temp,
                                                      float* __restrict__ attn)
{
    int h = blockIdx.x, bz = blockIdx.y;
    int t = threadIdx.x;
    int c = t >> 4, d = t & 15;
    float g = 0.f;
    for (int sl = 0; sl < 32; ++sl) g += part[((size_t)(bz * 8 + h) * 32 + sl) * 256 + t];
    float nqv = fmaxf(sqrtf(nqsq[bz * C_ + h * 16 + c]), 1e-12f);
    float nkv = fmaxf(sqrtf(nksq[bz * C_ + h * 16 + d]), 1e-12f);
    g *= temp[h] / (nqv * nkv);
    float m = g;
#pragma unroll
    for (int off = 8; off; off >>= 1) m = fmaxf(m, __shfl_xor(m, off, 16));
    float e = __expf(g - m);
    float ssum = e;
#pragma unroll
    for (int off = 8; off; off >>= 1) ssum += __shfl_xor(ssum, off, 16);
    attn[(bz * 8 + h) * 256 + t] = e / ssum;
}

__global__ __launch_bounds__(256) void av_kernel(const float* __restrict__ attn,
                                                 const float* __restrict__ V, size_t sv,
                                                 float* __restrict__ Y, size_t sy)
{
    __shared__ __align__(16) float kv[16][260];
    __shared__ __align__(16) float at[16][16];
    int tile = blockIdx.x, h = blockIdx.y, bz = blockIdx.z;
    int n0 = tile * 256, t = threadIdx.x;
    const float* vb = V + (size_t)bz * sv + (size_t)(h * 16) * HW_;
    at[t >> 4][t & 15] = attn[(size_t)(bz * 8 + h) * 256 + (t & 15) * 16 + (t >> 4)];
    for (int e = t; e < 16 * 256; e += 256) {
        int d = e >> 8, nn = e & 255;
        kv[d][nn] = vb[(size_t)d * HW_ + n0 + nn];
    }
    __syncthreads();
    float acc[16];
#pragma unroll
    for (int cc = 0; cc < 16; ++cc) acc[cc] = 0.f;
#pragma unroll
    for (int d = 0; d < 16; ++d) {
        float kvv = kv[d][t];
        float4 a0 = *(const float4*)&at[d][0];
        float4 a1 = *(const float4*)&at[d][4];
        float4 a2 = *(const float4*)&at[d][8];
        float4 a3 = *(const float4*)&at[d][12];
        acc[0]  += a0.x * kvv; acc[1]  += a0.y * kvv; acc[2]  += a0.z * kvv; acc[3]  += a0.w * kvv;
        acc[4]  += a1.x * kvv; acc[5]  += a1.y * kvv; acc[6]  += a1.z * kvv; acc[7]  += a1.w * kvv;
        acc[8]  += a2.x * kvv; acc[9]  += a2.y * kvv; acc[10] += a2.z * kvv; acc[11] += a2.w * kvv;
        acc[12] += a3.x * kvv; acc[13] += a3.y * kvv; acc[14] += a3.z * kvv; acc[15] += a3.w * kvv;
    }
    float* yb = Y + (size_t)bz * sy + (size_t)(h * 16) * HW_ + n0 + t;
#pragma unroll
    for (int cc = 0; cc < 16; ++cc) yb[(size_t)cc * HW_] = acc[cc];
}

// ---------------------------------------------------------------- 256-pt radix-2 DIT FFT core (32 lanes/row)
__device__ __forceinline__ void fft_stages(float2* row, const float2* tw, int lane)
{
#pragma unroll
    for (int s = 1; s <= 8; ++s) {
        const int half = 1 << (s - 1);
#pragma unroll
        for (int r = 0; r < 4; ++r) {
            int jb = lane + r * 32;
            int j = jb & (half - 1);
            int g = jb >> (s - 1);
            int i1 = (g << s) + j;
            float2 w = tw[j << (8 - s)];
            float2 u = row[i1];
            float2 q = row[i1 + half];
            float2 v = make_float2(q.x * w.x - q.y * w.y, q.x * w.y + q.y * w.x);
            row[i1]        = make_float2(u.x + v.x, u.y + v.y);
            row[i1 + half] = make_float2(u.x - v.x, u.y - v.y);
        }
        __syncthreads();
    }
}

#define PI2_ 6.28318530717958647692f

// real rows -> transposed spectrum T[c][k][h]
__global__ __launch_bounds__(256) void rfft_rowsT(const float* __restrict__ X, size_t sx,
                                                  float2* __restrict__ T, size_t st)
{
    __shared__ float2 sd[8][256];
    __shared__ float2 tw[128];
    int t = threadIdx.x;
    int bz = blockIdx.y;
    if (t < 128) { float sn, cs; __sincosf(-PI2_ * (float)t * (1.f / 256.f), &sn, &cs); tw[t] = make_float2(cs, sn); }
    size_t r0 = (size_t)blockIdx.x * 8;
    int c = (int)(r0 >> 8), h0 = (int)(r0 & 255);
    const float* Xb = X + (size_t)bz * sx;
    for (int e = t; e < 2048; e += 256) {
        int j = e >> 8, i = e & 255;
        sd[j][__brev((unsigned)i) >> 24] = make_float2(Xb[(r0 + j) * 256 + i], 0.f);
    }
    __syncthreads();
    fft_stages(sd[t >> 5], tw, t & 31);
    float2* base = T + (size_t)bz * st + (size_t)c * PLANEF_;
    for (int e = t; e < 8 * 129; e += 256) {
        int j = e & 7, k = e >> 3;
        base[(size_t)k * 256 + h0 + j] = sd[j][k];
    }
}

// forward complex FFT along h on transposed layout
__global__ __launch_bounds__(256) void cfftT_fwd(float2* __restrict__ T, size_t st)
{
    __shared__ float2 sd[8][256];
    __shared__ float2 tw[128];
    int t = threadIdx.x;
    int bz = blockIdx.z;
    if (t < 128) { float sn, cs; __sincosf(-PI2_ * (float)t * (1.f / 256.f), &sn, &cs); tw[t] = make_float2(cs, sn); }
    int k0 = blockIdx.x * 8;
    int c = blockIdx.y;
    float2* base = T + (size_t)bz * st + (size_t)c * PLANEF_;
    for (int e = t; e < 2048; e += 256) {
        int j = e >> 8, i = e & 255;
        int k = k0 + j;
        float2 v = (k < KF_) ? base[(size_t)k * 256 + i] : make_float2(0.f, 0.f);
        sd[j][__brev((unsigned)i) >> 24] = v;
    }
    __syncthreads();
    fft_stages(sd[t >> 5], tw, t & 31);
    for (int e = t; e < 2048; e += 256) {
        int j = e >> 8, i = e & 255;
        int k = k0 + j;
        if (k < KF_) base[(size_t)k * 256 + i] = sd[j][i];
    }
}

// combine(amp,pha) + inverse h-FFT; writes row-major spectrum S[c][h][k]
__global__ __launch_bounds__(256) void cifft_combine(const float* __restrict__ amp, size_t sa,
                                                     const float* __restrict__ pha, size_t sp,
                                                     float2* __restrict__ S, size_t ss)
{
    __shared__ float2 sd[8][256];
    __shared__ float2 tw[128];
    int t = threadIdx.x;
    int bz = blockIdx.z;
    if (t < 128) { float sn, cs; __sincosf(PI2_ * (float)t * (1.f / 256.f), &sn, &cs); tw[t] = make_float2(cs, sn); }
    int k0 = blockIdx.x * 8;
    int c = blockIdx.y;
    const float* ab = amp + (size_t)bz * sa + (size_t)c * PLANEF_;
    const float* pb = pha + (size_t)bz * sp + (size_t)c * PLANEF_;
    for (int e = t; e < 2048; e += 256) {
        int j = e >> 8, i = e & 255;
        int k = k0 + j;
        float2 v = make_float2(0.f, 0.f);
        if (k < KF_) {
            float a = ab[(size_t)k * 256 + i];
            float p = pb[(size_t)k * 256 + i];
            float sn, cs;
            __sincosf(p, &sn, &cs);
            v = make_float2(a * cs + 2e-8f, a * sn + 1e-8f);
        }
        sd[j][__brev((unsigned)i) >> 24] = v;
    }
    __syncthreads();
    fft_stages(sd[t >> 5], tw, t & 31);
    float2* base = S + (size_t)bz * ss + (size_t)c * PLANEF_;
    for (int e = t; e < 2048; e += 256) {
        int j = e & 7, h = e >> 3;
        int k = k0 + j;
        if (k < KF_) {
            float2 o = sd[j][h];
            base[(size_t)h * KF_ + k] = make_float2(o.x * (1.f / 256.f), o.y * (1.f / 256.f));
        }
    }
}

// row-major spectrum -> 256 real (Hermitian) -> |.|
__global__ __launch_bounds__(256) void irfft_rows8_abs(const float2* __restrict__ S, size_t ss,
                                                       float* __restrict__ Y, size_t sy)
{
    __shared__ float2 sd[8][256];
    __shared__ float2 tw[128];
    int t = threadIdx.x;
    int bz = blockIdx.y;
    if (t < 128) { float sn, cs; __sincosf(PI2_ * (float)t * (1.f / 256.f), &sn, &cs); tw[t] = make_float2(cs, sn); }
    size_t r0 = (size_t)blockIdx.x * 8;
    const float2* Sb = S + (size_t)bz * ss;
    for (int e = t; e < 2048; e += 256) {
        int j = e >> 8, i = e & 255;
        const float2* row = Sb + (r0 + j) * 129;
        float2 v;
        if (i < 129) v = row[i];
        else { float2 w2 = row[256 - i]; v = make_float2(w2.x, -w2.y); }
        sd[j][__brev((unsigned)i) >> 24] = v;
    }
    __syncthreads();
    fft_stages(sd[t >> 5], tw, t & 31);
    float* Yb = Y + (size_t)bz * sy;
    for (int e = t; e < 2048; e += 256) {
        int j = e >> 8, i = e & 255;
        Yb[(r0 + j) * 256 + i] = fabsf(sd[j][i].x * (1.f / 256.f));
    }
}

// ---------------------------------------------------------------- host
extern "C" void kernel_launch(void* const* d_in, const int* in_sizes, int n_in,
                              void* d_out, int out_size, void* d_ws, size_t ws_size,
                              hipStream_t stream)
{
    (void)in_sizes; (void)n_in; (void)out_size;
    const float* ms    = (const float*)d_in[0];
    const float* pan   = (const float*)d_in[1];
    const float* ln1w  = (const float*)d_in[2];
    const float* ln1b  = (const float*)d_in[3];
    const float* ln2w  = (const float*)d_in[4];
    const float* ln2b  = (const float*)d_in[5];
    const float* qkvw  = (const float*)d_in[6];
    const float* dww   = (const float*)d_in[7];
    const float* temp  = (const float*)d_in[8];
    const float* projw = (const float*)d_in[9];
    const float* pre1w = (const float*)d_in[10];
    const float* pre1b = (const float*)d_in[11];
    const float* pre2w = (const float*)d_in[12];
    const float* pre2b = (const float*)d_in[13];
    const float* amp1w = (const float*)d_in[14];
    const float* amp1b = (const float*)d_in[15];
    const float* amp2w = (const float*)d_in[16];
    const float* amp2b = (const float*)d_in[17];
    const float* pha1w = (const float*)d_in[18];
    const float* pha1b = (const float*)d_in[19];
    const float* pha2w = (const float*)d_in[20];
    const float* pha2b = (const float*)d_in[21];
    const float* postw = (const float*)d_in[22];
    const float* postb = (const float*)d_in[23];
    const float* pinw  = (const float*)d_in[24];
    const float* poutw = (const float*)d_in[25];

    const size_t WKSS = 8454144;   // 33.8 MB slot (floats)
    auto needf = [&](int nb) -> size_t {
        return (33554432ull + (size_t)nb * 3ull * WKSS + 524288ull) * 4ull;
    };
    int NB = (ws_size >= needf(4)) ? 4 : ((ws_size >= needf(2)) ? 2 : 1);

    float* F   = (float*)d_ws;                       // 33554432 f : frefuse (all batches)
    float* WK0 = F + 33554432;                       // NB slots; spatial scratch / AH+PH
    float* WK1 = WK0 + (size_t)NB * WKSS;            // q / msF spectrum / amp,pha
    float* WK2 = WK1 + (size_t)NB * WKSS;            // kv / panF spectrum / S
    unsigned short* w_qkv   = (unsigned short*)(WK2 + (size_t)NB * WKSS);
    unsigned short* w_proj  = w_qkv  + 16384;
    unsigned short* w_pre1  = w_proj + 16384;
    unsigned short* w_pre2  = w_pre1 + 16384;
    unsigned short* w_post  = w_pre2 + 16384;
    unsigned short* w_amp1  = w_post + 16384;   // [128][256]
    unsigned short* w_pha1  = w_amp1 + 32768;
    unsigned short* w_amp2  = w_pha1 + 32768;
    unsigned short* w_pha2  = w_amp2 + 16384;
    unsigned short* w_pin   = w_pha2 + 16384;   // [512][256] folded
    unsigned short* w_pout2 = w_pin  + 131072;  // [2][128][128]
    float* ksumP  = (float*)(w_pout2 + 32768);
    float* nqsq   = ksumP + 128;     // 512
    float* nksq   = nqsq  + 512;     // 512
    float* attnP  = nksq  + 512;     // 8192
    float* partP  = attnP + 8192;    // 262144
    float* qkv_ws = partP + 262144;
    float* qkv_bb = qkv_ws + 128;
    float* pin_ws = qkv_bb + 128;    // 512
    float* pin_bb = pin_ws + 512;    // 512
    float* pinC   = pin_bb + 512;    // 1024 (float4[256])

    float* xout = (float*)d_out;

    auto CVT = [&](const float* src, unsigned short* dst, int n) {
        tobf16_kernel<<<(n + 255) / 256, 256, 0, stream>>>(src, dst, n);
    };
    foldln_kernel<<<128, 128, 0, stream>>>(qkvw, ln1w, ln1b, w_qkv, qkv_ws, qkv_bb, 128);
    foldln_kernel<<<512, 128, 0, stream>>>(pinw, ln2w, ln2b, w_pin, pin_ws, pin_bb, 256);
    CVT(projw, w_proj, 16384);
    CVT(pre1w, w_pre1, 16384); CVT(pre2w, w_pre2, 16384);
    CVT(postw, w_post, 16384);
    CVT(amp1w, w_amp1, 32768); CVT(pha1w, w_pha1, 32768);
    CVT(amp2w, w_amp2, 16384); CVT(pha2w, w_pha2, 16384);
    poutperm_kernel<<<128, 256, 0, stream>>>(poutw, w_pout2);
    pinc_kernel<<<1, 256, 0, stream>>>(pin_bb, pin_ws, (float4*)pinC);
    ksum_kernel<<<1, 128, 0, stream>>>(dww, ksumP);

    const size_t CHW = (size_t)C_ * HW_;
    const size_t CPF = (size_t)C_ * PLANEF_;   // 4227072
    const float* NUL = nullptr;

    for (int b0 = 0; b0 < B_; b0 += NB) {
        const float* msb  = ms  + (size_t)b0 * CHW;
        const float* panb = pan + (size_t)b0 * CHW;
        float* xb   = xout + (size_t)b0 * CHW;
        float* freb = F    + (size_t)b0 * CHW;
        dim3 gz(512, 1, NB);
        dim3 gzf(258, 1, NB);

        // ---- attention ----
        zero2_kernel<<<(NB * 128 + 255) / 256, 256, 0, stream>>>(nqsq, nksq, NB * 128);
        mconv2<0, true><<<gz, 256, 0, stream>>>(
            msb, CHW, w_qkv, 128, nullptr, nullptr, 0, WK0, WKSS, HW_, 0, qkv_ws, qkv_bb);
        dwconv2<<<dim3(64, 128, NB), 256, 0, stream>>>(WK0, WKSS, dww, ksumP, WK1, WKSS, nqsq);   // q
        mconv2<0, true><<<gz, 256, 0, stream>>>(
            panb, CHW, w_qkv, 128, nullptr, nullptr, 0, WK0, WKSS, HW_, 0, qkv_ws, qkv_bb);
        dwconv2<<<dim3(64, 128, NB), 256, 0, stream>>>(WK0, WKSS, dww, ksumP, WK2, WKSS, nksq);   // kv
        gram_kernel<<<dim3(32, 8, NB), 256, 0, stream>>>(WK1, WKSS, WK2, WKSS, partP);
        softmax_kernel<<<dim3(8, NB), 256, 0, stream>>>(partP, nqsq, nksq, temp, attnP);
        av_kernel<<<dim3(256, 8, NB), 256, 0, stream>>>(attnP, WK2, WKSS, WK0, WKSS);
        mconv2<0, false><<<gz, 256, 0, stream>>>(
            WK0, WKSS, w_proj, 128, nullptr, msb, CHW, xb, CHW, HW_, 0, NUL, NUL);

        // ---- freprocess ----
        mconv2<0, false><<<gz, 256, 0, stream>>>(
            msb, CHW, w_pre1, 128, pre1b, nullptr, 0, WK0, WKSS, HW_, 1, NUL, NUL);
        rfft_rowsT<<<dim3(4096, NB), 256, 0, stream>>>(WK0, WKSS, (float2*)WK1, WKSS / 2);
        cfftT_fwd<<<dim3(17, 128, NB), 256, 0, stream>>>((float2*)WK1, WKSS / 2);
        mconv2<0, false><<<gz, 256, 0, stream>>>(
            panb, CHW, w_pre2, 128, pre2b, nullptr, 0, WK0, WKSS, HW_, 1, NUL, NUL);
        rfft_rowsT<<<dim3(4096, NB), 256, 0, stream>>>(WK0, WKSS, (float2*)WK2, WKSS / 2);
        cfftT_fwd<<<dim3(17, 128, NB), 256, 0, stream>>>((float2*)WK2, WKSS / 2);
        // fused amp1+pha1 over both spectra; AH/PH overlay the (dead) WK0 slot
        apconv<<<gzf, 256, 0, stream>>>(
            (const float2*)WK1, (const float2*)WK2, WKSS / 2,
            w_amp1, w_pha1, amp1b, pha1b, WK0, WK0 + CPF, WKSS);
        mconv2<1, false><<<gzf, 256, 0, stream>>>(            // amp = amp2(leaky(AH))
            WK0, WKSS, w_amp2, 128, amp2b, nullptr, 0, WK1, WKSS, PLANEF_, 0, NUL, NUL);
        mconv2<1, false><<<gzf, 256, 0, stream>>>(            // pha = pha2(leaky(PH))
            WK0 + CPF, WKSS, w_pha2, 128, pha2b, nullptr, 0, WK1 + CPF, WKSS, PLANEF_, 0, NUL, NUL);
        cifft_combine<<<dim3(17, 128, NB), 256, 0, stream>>>(WK1, WKSS, WK1 + CPF, WKSS, (float2*)WK2, WKSS / 2);
        irfft_rows8_abs<<<dim3(4096, NB), 256, 0, stream>>>((float2*)WK2, WKSS / 2, WK0, WKSS);
        mconv2<0, false><<<gz, 256, 0, stream>>>(
            WK0, WKSS, w_post, 128, postb, nullptr, 0, freb, CHW, HW_, 0, NUL, NUL);
    }

    // ---- FFN (full batch, LN2 + gelu-gate fused) ----
    ffn_mfma4<<<dim3(HW_ / 64, B_), 256, 0, stream>>>(xout, F, w_pin, w_pout2, (const float4*)pinC, xout);
}

// Round 8
// 1861.264 us; speedup vs baseline: 1.3443x; 1.3443x over previous
//
#include <hip/hip_runtime.h>
#include <math.h>

#define B_ 4
#define C_ 128
#define HW_ 65536
#define H__ 256
#define KF_ 129
#define PLANEF_ 33024

typedef __attribute__((ext_vector_type(8))) short short8v;
typedef __attribute__((ext_vector_type(4))) float f32x4;
typedef __attribute__((ext_vector_type(4))) unsigned short ush4;
typedef __attribute__((ext_vector_type(8))) unsigned short ush8;

__device__ __forceinline__ unsigned short f2bf(float f) {
    union { float f; unsigned u; } v; v.f = f;
    return (unsigned short)((v.u + 0x7FFFu + ((v.u >> 16) & 1u)) >> 16);
}
__device__ __forceinline__ float bf2f(unsigned short s) {
    union { unsigned u; float f; } v; v.u = (unsigned)s << 16;
    return v.f;
}
__device__ __forceinline__ unsigned pack2bf(float2 v) {
    return (unsigned)f2bf(v.x) | ((unsigned)f2bf(v.y) << 16);
}
__device__ __forceinline__ float2 upk(unsigned u) {
    return make_float2(bf2f((unsigned short)(u & 0xffff)), bf2f((unsigned short)(u >> 16)));
}
// fast gelu: A&S 7.1.26 erf (|err|<=1.5e-7) with __expf
__device__ __forceinline__ float geluf(float x) {
    float z = 0.70710678118654752f * fabsf(x);
    float t = __fdividef(1.f, fmaf(0.3275911f, z, 1.f));
    float p = fmaf(1.061405429f, t, -1.453152027f);
    p = fmaf(p, t, 1.421413741f);
    p = fmaf(p, t, -0.284496736f);
    p = fmaf(p, t, 0.254829592f);
    p = p * t;
    float erfv = 1.f - p * __expf(-z * z);
    float cdf = (x >= 0.f) ? fmaf(0.5f, erfv, 0.5f) : fmaf(-0.5f, erfv, 0.5f);
    return x * cdf;
}
// fast atan2, poly err ~1e-5 rad
__device__ __forceinline__ float fatan2(float y, float x) {
    float ax = fabsf(x), ay = fabsf(y);
    float mx = fmaxf(ax, ay), mn = fminf(ax, ay);
    float a = __fdividef(mn, fmaxf(mx, 1e-38f));
    float s = a * a;
    float r = fmaf(0.0208351f, s, -0.0851330f);
    r = fmaf(r, s, 0.1801410f);
    r = fmaf(r, s, -0.3302995f);
    r = fmaf(r, s, 0.9998660f);
    r = r * a;
    if (ay > ax) r = 1.57079632679489662f - r;
    if (x < 0.f) r = 3.14159265358979324f - r;
    return copysignf(r, y);
}
// LDS XOR swizzle on byte-offset within row
template<int W>
__device__ __forceinline__ char* swz_ptr(unsigned short (*xs)[W], int px, int cb) {
    return (char*)xs + px * (W * 2) + (cb ^ (((px >> 2) & 7) << 4));
}

// ---------------------------------------------------------------- prep
__global__ __launch_bounds__(256) void tobf16_kernel(const float* __restrict__ src,
                                                     unsigned short* __restrict__ dst, int n)
{
    int i = blockIdx.x * 256 + threadIdx.x;
    if (i < n) dst[i] = f2bf(src[i]);
}

__global__ __launch_bounds__(128) void foldln_kernel(const float* __restrict__ W,
                                                     const float* __restrict__ lnw,
                                                     const float* __restrict__ lnb,
                                                     unsigned short* __restrict__ Wb,
                                                     float* __restrict__ wsum, float* __restrict__ bsum,
                                                     int Cc)
{
    int o = blockIdx.x, t = threadIdx.x;
    float sw = 0.f, sb = 0.f;
    for (int c = t; c < Cc; c += 128) {
        float w = W[(size_t)o * Cc + c];
        float fw = w * lnw[c];
        unsigned short us = f2bf(fw);
        Wb[(size_t)o * Cc + c] = us;
        sw += bf2f(us);
        sb += w * lnb[c];
    }
    __shared__ float r1[128], r2[128];
    r1[t] = sw; r2[t] = sb; __syncthreads();
    for (int st = 64; st; st >>= 1) {
        if (t < st) { r1[t] += r1[t + st]; r2[t] += r2[t + st]; }
        __syncthreads();
    }
    if (!t) { wsum[o] = r1[0]; bsum[o] = r2[0]; }
}

__global__ __launch_bounds__(256) void poutperm_kernel(const float* __restrict__ src,
                                                       unsigned short* __restrict__ dst)
{
    int i = blockIdx.x * 256 + threadIdx.x;   // 32768
    int half = i >> 14, rem = i & 16383, o = rem >> 7, kp = rem & 127;
    int h = (kp >> 5) * 64 + half * 32 + (kp & 31);
    dst[i] = f2bf(src[o * 256 + h]);
}

__global__ void pinc_kernel(const float* __restrict__ bb, const float* __restrict__ ws,
                            float4* __restrict__ pinC)
{
    int i = threadIdx.x;
    if (i < 256) pinC[i] = make_float4(bb[i], ws[i], bb[i + 256], ws[i + 256]);
}

__global__ void ksum_kernel(const float* __restrict__ dw, float* __restrict__ ks)
{
    int c = threadIdx.x;
    if (c < C_) {
        float s = 0.f;
        for (int k = 0; k < 9; ++k) s += dw[c * 9 + k];
        ks[c] = s;
    }
}

__global__ __launch_bounds__(256) void zero2_kernel(float* __restrict__ a, float* __restrict__ b, int n)
{
    int i = blockIdx.x * 256 + threadIdx.x;
    if (i < n) { a[i] = 0.f; b[i] = 0.f; }
}

// ---------------------------------------------------------------- MFMA conv1x1 (CIN=128)
// INBF: input dtype 0=f32 1=bf16. OUTBF: output dtype. PRO==1: leaky(0.1) on staged value.
// LNF: register LN stats + folded-affine epilogue (requires INBF=0). flags&1: +1e-8 after bias.
template<int INBF, int OUTBF, int PRO, bool LNF>
__global__ __launch_bounds__(256, 3) void mconv2(
    const void* __restrict__ Xv, size_t sx,
    const unsigned short* __restrict__ Wb, int wstride,
    const float* __restrict__ bias,
    const float* __restrict__ res, size_t sres,
    void* __restrict__ Yv, size_t sy, int plane, int flags,
    const float* __restrict__ wsum, const float* __restrict__ bsum)
{
    __shared__ unsigned short xs[128][136];
    __shared__ float2 lnred[LNF ? 8 : 1][LNF ? 128 : 1];
    __shared__ float2 lnmi[LNF ? 128 : 1];
    const int t = threadIdx.x;
    const int bz = blockIdx.z;
    const int p0 = blockIdx.x * 128;
    const int lane = t & 63;
    const int wr = t >> 7, wc = (t >> 6) & 1;
    const int lr = lane >> 4, lc = lane & 15;

    if constexpr (INBF == 0) {
        const float* Xb = (const float*)Xv + (size_t)bz * sx;
        const int px4 = t & 31;
        float s0 = 0.f, s1 = 0.f, s2v = 0.f, s3 = 0.f;
        float q0 = 0.f, q1 = 0.f, q2 = 0.f, q3 = 0.f;
#pragma unroll
        for (int g = 0; g < 2; ++g) {
            float4 st[8];
#pragma unroll
            for (int i = 0; i < 8; ++i) {
                int e = t + (g * 8 + i) * 256;           // 4096 items: 128c x 32 px4
                int c = e >> 5;
                st[i] = *(const float4*)(Xb + (size_t)c * plane + p0 + px4 * 4);
            }
#pragma unroll
            for (int i = 0; i < 8; ++i) {
                int e = t + (g * 8 + i) * 256;
                int c = e >> 5;
                float a0 = st[i].x, a1 = st[i].y, a2 = st[i].z, a3 = st[i].w;
                if constexpr (PRO == 1) {
                    a0 = a0 > 0.f ? a0 : 0.1f * a0;
                    a1 = a1 > 0.f ? a1 : 0.1f * a1;
                    a2 = a2 > 0.f ? a2 : 0.1f * a2;
                    a3 = a3 > 0.f ? a3 : 0.1f * a3;
                }
                if constexpr (LNF) {
                    s0 += a0; q0 += a0 * a0;
                    s1 += a1; q1 += a1 * a1;
                    s2v += a2; q2 += a2 * a2;
                    s3 += a3; q3 += a3 * a3;
                }
                *(unsigned short*)swz_ptr(xs, px4 * 4 + 0, 2 * c) = f2bf(a0);
                *(unsigned short*)swz_ptr(xs, px4 * 4 + 1, 2 * c) = f2bf(a1);
                *(unsigned short*)swz_ptr(xs, px4 * 4 + 2, 2 * c) = f2bf(a2);
                *(unsigned short*)swz_ptr(xs, px4 * 4 + 3, 2 * c) = f2bf(a3);
            }
        }
        if constexpr (LNF) {
            lnred[t >> 5][px4 * 4 + 0] = make_float2(s0, q0);
            lnred[t >> 5][px4 * 4 + 1] = make_float2(s1, q1);
            lnred[t >> 5][px4 * 4 + 2] = make_float2(s2v, q2);
            lnred[t >> 5][px4 * 4 + 3] = make_float2(s3, q3);
        }
    } else {
        const unsigned short* Xb = (const unsigned short*)Xv + (size_t)bz * sx;
        ush8 st[8];
#pragma unroll
        for (int i = 0; i < 8; ++i) {
            int e = t + i * 256;                         // 2048 items: 128c x 16 px8
            int c = e >> 4, px8 = e & 15;
            st[i] = *(const ush8*)(Xb + (size_t)c * plane + p0 + px8 * 8);
        }
#pragma unroll
        for (int i = 0; i < 8; ++i) {
            int e = t + i * 256;
            int c = e >> 4, px8 = e & 15;
#pragma unroll
            for (int j = 0; j < 8; ++j) {
                unsigned short us = (unsigned short)st[i][j];
                if constexpr (PRO == 1) {
                    float f = bf2f(us);
                    f = f > 0.f ? f : 0.1f * f;
                    us = f2bf(f);
                }
                *(unsigned short*)swz_ptr(xs, px8 * 8 + j, 2 * c) = us;
            }
        }
    }
    __syncthreads();
    if constexpr (LNF) {
        if (t < 128) {
            float ss = 0.f, qq = 0.f;
#pragma unroll
            for (int j = 0; j < 8; ++j) { float2 a = lnred[j][t]; ss += a.x; qq += a.y; }
            float m = ss * (1.f / 128.f);
            float inv = rsqrtf(qq * (1.f / 128.f) - m * m + 1e-5f);
            lnmi[t] = make_float2(m, inv);
        }
        __syncthreads();
    }

    f32x4 acc[4][4];
#pragma unroll
    for (int mi = 0; mi < 4; ++mi)
#pragma unroll
        for (int ni = 0; ni < 4; ++ni) acc[mi][ni] = (f32x4){0.f, 0.f, 0.f, 0.f};

#pragma unroll
    for (int kk = 0; kk < 128; kk += 32) {
        short8v bfr[4];
#pragma unroll
        for (int ni = 0; ni < 4; ++ni)
            bfr[ni] = *(const short8v*)swz_ptr(xs, wc * 64 + ni * 16 + lc, 2 * (kk + lr * 8));
#pragma unroll
        for (int mi = 0; mi < 4; ++mi) {
            int row = wr * 64 + mi * 16 + lc;
            short8v afr = *(const short8v*)(Wb + (size_t)row * wstride + kk + lr * 8);
#pragma unroll
            for (int ni = 0; ni < 4; ++ni)
                acc[mi][ni] = __builtin_amdgcn_mfma_f32_16x16x32_bf16(afr, bfr[ni], acc[mi][ni], 0, 0, 0);
        }
    }

    float2 mrow[4];
    if constexpr (LNF) {
#pragma unroll
        for (int ni = 0; ni < 4; ++ni) mrow[ni] = lnmi[wc * 64 + ni * 16 + lc];
    }

#pragma unroll
    for (int mi = 0; mi < 4; ++mi) {
        int ob = wr * 64 + mi * 16 + lr * 4;
#pragma unroll
        for (int r = 0; r < 4; ++r) {
            int o = ob + r;
            float bv = 0.f, wso = 0.f;
            if constexpr (LNF) { bv = bsum[o]; wso = wsum[o]; }
            else { if (bias) bv = bias[o]; if (flags & 1) bv += 1e-8f; }
#pragma unroll
            for (int ni = 0; ni < 4; ++ni) {
                int px = wc * 64 + ni * 16 + lc;
                float v;
                if constexpr (LNF) {
                    float m = mrow[ni].x, inv = mrow[ni].y;
                    v = acc[mi][ni][r] * inv + bv - m * inv * wso;
                } else {
                    v = acc[mi][ni][r] + bv;
                }
                if constexpr (OUTBF == 0) {
                    float* Y = (float*)Yv;
                    size_t yi = (size_t)bz * sy + (size_t)o * plane + p0 + px;
                    if (res) v += res[(size_t)bz * sres + (size_t)o * plane + p0 + px];
                    Y[yi] = v;
                } else {
                    unsigned short* Y = (unsigned short*)Yv;
                    Y[(size_t)bz * sy + (size_t)o * plane + p0 + px] = f2bf(v);
                }
            }
        }
    }
}

// ---------------------------------------------------------------- fused amp1+pha1 spectral conv (CIN=256, two bf16 spectra)
__global__ __launch_bounds__(256, 2) void apconv(
    const unsigned* __restrict__ T1, const unsigned* __restrict__ T2, size_t sT,
    const unsigned short* __restrict__ Wa, const unsigned short* __restrict__ Wp,
    const float* __restrict__ ba, const float* __restrict__ bp,
    unsigned short* __restrict__ AH, unsigned short* __restrict__ PH, size_t sO)
{
    __shared__ unsigned short xa[128][72];
    __shared__ unsigned short xp[128][72];
    const int t = threadIdx.x;
    const int bz = blockIdx.z;
    const int p0 = blockIdx.x * 128;
    const int lane = t & 63;
    const int wr = t >> 7, wc = (t >> 6) & 1;
    const int lr = lane >> 4, lc = lane & 15;
    const int px2 = t & 63;

    f32x4 aa[4][4], ap[4][4];
#pragma unroll
    for (int mi = 0; mi < 4; ++mi)
#pragma unroll
        for (int ni = 0; ni < 4; ++ni) { aa[mi][ni] = (f32x4){0.f,0.f,0.f,0.f}; ap[mi][ni] = (f32x4){0.f,0.f,0.f,0.f}; }

    for (int ch = 0; ch < 256; ch += 64) {
        const unsigned* Ts = ((ch < 128) ? T1 : T2) + (size_t)bz * sT + (size_t)(ch & 127) * PLANEF_;
#pragma unroll
        for (int g = 0; g < 2; ++g) {
            uint2 st[8];
#pragma unroll
            for (int i = 0; i < 8; ++i) {
                int e = t + (g * 8 + i) * 256;       // 4096 items: 64c x 64 px2 (=128 px)
                int c = e >> 6;
                st[i] = *(const uint2*)(Ts + (size_t)c * PLANEF_ + p0 + px2 * 2);
            }
#pragma unroll
            for (int i = 0; i < 8; ++i) {
                int e = t + (g * 8 + i) * 256;
                int c = e >> 6;
                float2 z0 = upk(st[i].x), z1 = upk(st[i].y);
                float m0 = sqrtf(z0.x * z0.x + z0.y * z0.y);
                float m1 = sqrtf(z1.x * z1.x + z1.y * z1.y);
                float a0 = fatan2(z0.y, z0.x);
                float a1 = fatan2(z1.y, z1.x);
                *(unsigned short*)swz_ptr(xa, px2 * 2 + 0, 2 * c) = f2bf(m0);
                *(unsigned short*)swz_ptr(xa, px2 * 2 + 1, 2 * c) = f2bf(m1);
                *(unsigned short*)swz_ptr(xp, px2 * 2 + 0, 2 * c) = f2bf(a0);
                *(unsigned short*)swz_ptr(xp, px2 * 2 + 1, 2 * c) = f2bf(a1);
            }
        }
        __syncthreads();
#pragma unroll
        for (int kk = 0; kk < 64; kk += 32) {
            short8v bfa[4], bfp[4];
#pragma unroll
            for (int ni = 0; ni < 4; ++ni) {
                bfa[ni] = *(const short8v*)swz_ptr(xa, wc * 64 + ni * 16 + lc, 2 * (kk + lr * 8));
                bfp[ni] = *(const short8v*)swz_ptr(xp, wc * 64 + ni * 16 + lc, 2 * (kk + lr * 8));
            }
#pragma unroll
            for (int mi = 0; mi < 4; ++mi) {
                int row = wr * 64 + mi * 16 + lc;
                short8v afa = *(const short8v*)(Wa + (size_t)row * 256 + ch + kk + lr * 8);
                short8v afp = *(const short8v*)(Wp + (size_t)row * 256 + ch + kk + lr * 8);
#pragma unroll
                for (int ni = 0; ni < 4; ++ni) {
                    aa[mi][ni] = __builtin_amdgcn_mfma_f32_16x16x32_bf16(afa, bfa[ni], aa[mi][ni], 0, 0, 0);
                    ap[mi][ni] = __builtin_amdgcn_mfma_f32_16x16x32_bf16(afp, bfp[ni], ap[mi][ni], 0, 0, 0);
                }
            }
        }
        __syncthreads();
    }

#pragma unroll
    for (int mi = 0; mi < 4; ++mi) {
        int ob = wr * 64 + mi * 16 + lr * 4;
#pragma unroll
        for (int r = 0; r < 4; ++r) {
            int o = ob + r;
            float bva = ba[o], bvp = bp[o];
#pragma unroll
            for (int ni = 0; ni < 4; ++ni) {
                int px = wc * 64 + ni * 16 + lc;
                size_t yi = (size_t)bz * sO + (size_t)o * PLANEF_ + p0 + px;
                AH[yi] = f2bf(aa[mi][ni][r] + bva);
                PH[yi] = f2bf(ap[mi][ni][r] + bvp);
            }
        }
    }
}

// ---------------------------------------------------------------- fused MFMA FFN (x f32, fre bf16)
__global__ __launch_bounds__(256, 3) void ffn_mfma5(
    const float* __restrict__ x, const unsigned short* __restrict__ fre,
    const unsigned short* __restrict__ pinb,    // [512][256] folded bf16
    const unsigned short* __restrict__ pout2,   // [2][128][128] permuted bf16
    const float4* __restrict__ pinC,            // [256] (bb1,ws1,bb2,ws2)
    float* __restrict__ out)
{
    __shared__ unsigned short xs[64][264];
    __shared__ unsigned short hs[64][136];
    __shared__ float2 muinv[64];
    float2* sred = (float2*)&hs[0][0];          // overlay: dead until GEMM1 epilogue
    const int b = blockIdx.y;
    const size_t p0 = (size_t)blockIdx.x * 64;
    const int t = threadIdx.x;
    const int wave = t >> 6, lane = t & 63;
    const int lr = lane >> 4, lc = lane & 15;
    const int px4 = t & 15;

    float s0 = 0.f, s1 = 0.f, s2v = 0.f, s3 = 0.f;
    float q0 = 0.f, q1 = 0.f, q2 = 0.f, q3 = 0.f;
    {
        float4 stx[8];
        ush4 stf[8];
#pragma unroll
        for (int i = 0; i < 8; ++i) {
            int e = t + i * 256;                 // 2048 items: 128c x 16 px4
            int c = e >> 4;
            stx[i] = *(const float4*)(x + ((size_t)b * 128 + c) * HW_ + p0 + px4 * 4);
        }
#pragma unroll
        for (int i = 0; i < 8; ++i) {
            int e = t + i * 256;
            int c = e >> 4;
            stf[i] = *(const ush4*)(fre + (size_t)b * 8388608 + (size_t)c * HW_ + p0 + px4 * 4);
        }
#pragma unroll
        for (int i = 0; i < 8; ++i) {
            int e = t + i * 256;
            int c = e >> 4;
            float a0 = stx[i].x, a1 = stx[i].y, a2 = stx[i].z, a3 = stx[i].w;
            s0 += a0; q0 += a0 * a0;
            s1 += a1; q1 += a1 * a1;
            s2v += a2; q2 += a2 * a2;
            s3 += a3; q3 += a3 * a3;
            *(unsigned short*)swz_ptr(xs, px4 * 4 + 0, 2 * c) = f2bf(a0);
            *(unsigned short*)swz_ptr(xs, px4 * 4 + 1, 2 * c) = f2bf(a1);
            *(unsigned short*)swz_ptr(xs, px4 * 4 + 2, 2 * c) = f2bf(a2);
            *(unsigned short*)swz_ptr(xs, px4 * 4 + 3, 2 * c) = f2bf(a3);
        }
#pragma unroll
        for (int i = 0; i < 8; ++i) {
            int e = t + i * 256;
            int c = e >> 4;
            float a0 = bf2f((unsigned short)stf[i][0]);
            float a1 = bf2f((unsigned short)stf[i][1]);
            float a2 = bf2f((unsigned short)stf[i][2]);
            float a3 = bf2f((unsigned short)stf[i][3]);
            s0 += a0; q0 += a0 * a0;
            s1 += a1; q1 += a1 * a1;
            s2v += a2; q2 += a2 * a2;
            s3 += a3; q3 += a3 * a3;
            *(unsigned short*)swz_ptr(xs, px4 * 4 + 0, 2 * (128 + c)) = (unsigned short)stf[i][0];
            *(unsigned short*)swz_ptr(xs, px4 * 4 + 1, 2 * (128 + c)) = (unsigned short)stf[i][1];
            *(unsigned short*)swz_ptr(xs, px4 * 4 + 2, 2 * (128 + c)) = (unsigned short)stf[i][2];
            *(unsigned short*)swz_ptr(xs, px4 * 4 + 3, 2 * (128 + c)) = (unsigned short)stf[i][3];
        }
    }
    sred[(t >> 4) * 64 + px4 * 4 + 0] = make_float2(s0, q0);
    sred[(t >> 4) * 64 + px4 * 4 + 1] = make_float2(s1, q1);
    sred[(t >> 4) * 64 + px4 * 4 + 2] = make_float2(s2v, q2);
    sred[(t >> 4) * 64 + px4 * 4 + 3] = make_float2(s3, q3);
    __syncthreads();
    if (t < 64) {
        float ss = 0.f, qq = 0.f;
#pragma unroll
        for (int j = 0; j < 16; ++j) { float2 a = sred[j * 64 + t]; ss += a.x; qq += a.y; }
        float m = ss * (1.f / 256.f);
        float inv = rsqrtf(qq * (1.f / 256.f) - m * m + 1e-5f);
        muinv[t] = make_float2(m, inv);
    }
    __syncthreads();

    float2 mrow[4];
#pragma unroll
    for (int ni = 0; ni < 4; ++ni) mrow[ni] = muinv[ni * 16 + lc];

    f32x4 oc[2][4];
#pragma unroll
    for (int mi = 0; mi < 2; ++mi)
#pragma unroll
        for (int ni = 0; ni < 4; ++ni) oc[mi][ni] = (f32x4){0.f, 0.f, 0.f, 0.f};

#pragma unroll
    for (int half = 0; half < 2; ++half) {
        f32x4 a1[2][4], a2[2][4];
#pragma unroll
        for (int mi = 0; mi < 2; ++mi)
#pragma unroll
            for (int ni = 0; ni < 4; ++ni) { a1[mi][ni] = (f32x4){0.f,0.f,0.f,0.f}; a2[mi][ni] = (f32x4){0.f,0.f,0.f,0.f}; }

#pragma unroll
        for (int k0 = 0; k0 < 256; k0 += 32) {
            short8v bfr[4];
#pragma unroll
            for (int ni = 0; ni < 4; ++ni)
                bfr[ni] = *(const short8v*)swz_ptr(xs, ni * 16 + lc, 2 * (k0 + lr * 8));
#pragma unroll
            for (int mi = 0; mi < 2; ++mi) {
                int hrow = wave * 64 + half * 32 + mi * 16 + lc;
                short8v af1 = *(const short8v*)(pinb + (size_t)hrow * 256 + k0 + lr * 8);
                short8v af2 = *(const short8v*)(pinb + (size_t)(hrow + 256) * 256 + k0 + lr * 8);
#pragma unroll
                for (int ni = 0; ni < 4; ++ni) {
                    a1[mi][ni] = __builtin_amdgcn_mfma_f32_16x16x32_bf16(af1, bfr[ni], a1[mi][ni], 0, 0, 0);
                    a2[mi][ni] = __builtin_amdgcn_mfma_f32_16x16x32_bf16(af2, bfr[ni], a2[mi][ni], 0, 0, 0);
                }
            }
        }
        __syncthreads();
#pragma unroll
        for (int mi = 0; mi < 2; ++mi)
#pragma unroll
            for (int r = 0; r < 4; ++r) {
                int ho = wave * 64 + half * 32 + mi * 16 + lr * 4 + r;
                float4 bwc = pinC[ho];
                int kp = wave * 32 + mi * 16 + lr * 4 + r;
#pragma unroll
                for (int ni = 0; ni < 4; ++ni) {
                    float m = mrow[ni].x, inv = mrow[ni].y;
                    float v1 = a1[mi][ni][r] * inv + bwc.x - m * inv * bwc.y;
                    float v2 = a2[mi][ni][r] * inv + bwc.z - m * inv * bwc.w;
                    hs[ni * 16 + lc][kp] = f2bf(geluf(v1) * v2);
                }
            }
        __syncthreads();
#pragma unroll
        for (int k0 = 0; k0 < 128; k0 += 32) {
            short8v bfr2[4];
#pragma unroll
            for (int ni = 0; ni < 4; ++ni)
                bfr2[ni] = *(const short8v*)&hs[ni * 16 + lc][k0 + lr * 8];
#pragma unroll
            for (int mi = 0; mi < 2; ++mi) {
                int orow = wave * 32 + mi * 16 + lc;
                short8v af = *(const short8v*)(pout2 + half * 16384 + orow * 128 + k0 + lr * 8);
#pragma unroll
                for (int ni = 0; ni < 4; ++ni)
                    oc[mi][ni] = __builtin_amdgcn_mfma_f32_16x16x32_bf16(af, bfr2[ni], oc[mi][ni], 0, 0, 0);
            }
        }
    }

#pragma unroll
    for (int mi = 0; mi < 2; ++mi)
#pragma unroll
        for (int r = 0; r < 4; ++r) {
            int o = wave * 32 + mi * 16 + lr * 4 + r;
#pragma unroll
            for (int ni = 0; ni < 4; ++ni) {
                size_t yi = ((size_t)b * 128 + o) * HW_ + p0 + ni * 16 + lc;
                out[yi] = oc[mi][ni][r] + x[yi];
            }
        }
}

// ---------------------------------------------------------------- depthwise 3x3 cd-conv (bf16 in/out) + fused sum-of-squares
__global__ __launch_bounds__(256) void dwconv2(const unsigned short* __restrict__ X, size_t sx,
                                               const float* __restrict__ w9,
                                               const float* __restrict__ ksum,
                                               unsigned short* __restrict__ Y, size_t sy,
                                               float* __restrict__ ssq)
{
    int bz = blockIdx.z;
    int c = blockIdx.y;
    int p4 = blockIdx.x * 256 + threadIdx.x;
    int p0 = p4 * 4;
    int i = p0 >> 8, j0 = p0 & 255;
    const unsigned short* xp = X + (size_t)bz * sx + (size_t)c * HW_;
    const float* wc = w9 + c * 9;
    float a[4] = {0.f, 0.f, 0.f, 0.f};
    float ctr[4];
#pragma unroll
    for (int di = -1; di <= 1; ++di) {
        int ii = i + di;
        if (ii < 0 || ii > 255) continue;
        const unsigned short* row = xp + ii * 256;
        ush4 m4 = *(const ush4*)(row + j0);
        float lft = (j0 > 0) ? bf2f(row[j0 - 1]) : 0.f;
        float rgt = (j0 < 252) ? bf2f(row[j0 + 4]) : 0.f;
        float v[6] = {lft, bf2f((unsigned short)m4[0]), bf2f((unsigned short)m4[1]),
                      bf2f((unsigned short)m4[2]), bf2f((unsigned short)m4[3]), rgt};
        if (di == 0) { ctr[0] = v[1]; ctr[1] = v[2]; ctr[2] = v[3]; ctr[3] = v[4]; }
        float w0 = wc[(di + 1) * 3], w1 = wc[(di + 1) * 3 + 1], w2 = wc[(di + 1) * 3 + 2];
#pragma unroll
        for (int k = 0; k < 4; ++k) a[k] += w0 * v[k] + w1 * v[k + 1] + w2 * v[k + 2];
    }
    float km = 0.7f * ksum[c];
    float o0 = a[0] - km * ctr[0], o1 = a[1] - km * ctr[1];
    float o2 = a[2] - km * ctr[2], o3 = a[3] - km * ctr[3];
    ush4 ov;
    ov[0] = f2bf(o0); ov[1] = f2bf(o1); ov[2] = f2bf(o2); ov[3] = f2bf(o3);
    *(ush4*)(Y + (size_t)bz * sy + (size_t)c * HW_ + p0) = ov;

    float q = o0 * o0 + o1 * o1 + o2 * o2 + o3 * o3;
    __shared__ float red[256];
    red[threadIdx.x] = q; __syncthreads();
    for (int st = 128; st; st >>= 1) {
        if (threadIdx.x < st) red[threadIdx.x] += red[threadIdx.x + st];
        __syncthreads();
    }
    if (!threadIdx.x) atomicAdd(&ssq[bz * C_ + c], red[0]);
}

// ---------------------------------------------------------------- attention helpers (bf16 q/k/v)
__global__ __launch_bounds__(256) void gram_kernel(const unsigned short* __restrict__ Q, size_t sq,
                                                   const unsigned short* __restrict__ K, size_t sk,
                                                   float* __restrict__ part)
{
    int sl = blockIdx.x, h = blockIdx.y, bz = blockIdx.z;
    const unsigned short* qb = Q + (size_t)bz * sq + (size_t)(h * 16) * HW_;
    const unsigned short* kb = K + (size_t)bz * sk + (size_t)(h * 16) * HW_;
    __shared__ __align__(16) float qs[16][68];
    __shared__ __align__(16) float ks[16][68];
    int c = threadIdx.x >> 4, d = threadIdx.x & 15;
    float acc = 0.f;
    for (int n0 = sl * 2048; n0 < (sl + 1) * 2048; n0 += 64) {
        {
            int cc = threadIdx.x >> 4, nn4 = threadIdx.x & 15;
            ush4 qv = *(const ush4*)(qb + (size_t)cc * HW_ + n0 + nn4 * 4);
            ush4 kv = *(const ush4*)(kb + (size_t)cc * HW_ + n0 + nn4 * 4);
#pragma unroll
            for (int j = 0; j < 4; ++j) {
                qs[cc][nn4 * 4 + j] = bf2f((unsigned short)qv[j]);
                ks[cc][nn4 * 4 + j] = bf2f((unsigned short)kv[j]);
            }
        }
        __syncthreads();
#pragma unroll
        for (int nn = 0; nn < 64; nn += 4) {
            float4 qv = *(const float4*)&qs[c][nn];
            float4 kv = *(const float4*)&ks[d][nn];
            acc += qv.x * kv.x + qv.y * kv.y + qv.z * kv.z + qv.w * kv.w;
        }
        __syncthreads();
    }
    part[((size_t)(bz * 8 + h) * 32 + sl) * 256 + threadIdx.x] = acc;
}

__global__ __launch_bounds__(256) void softmax_kernel(const float* __restrict__ part,
                                                      const float* __restrict__ nqsq,
                                                      const float* __restrict__ nksq,
                                                      const float* __restrict__ temp,
                                                      float* __restrict__ attn)
{
    int h = blockIdx.x, bz = blockIdx.y;
    int t = threadIdx.x;
    int c = t >> 4, d = t & 15;
    float g = 0.f;
    for (int sl = 0; sl < 32; ++sl) g += part[((size_t)(bz * 8 + h) * 32 + sl) * 256 + t];
    float nqv = fmaxf(sqrtf(nqsq[bz * C_ + h * 16 + c]), 1e-12f);
    float nkv = fmaxf(sqrtf(nksq[bz * C_ + h * 16 + d]), 1e-12f);
    g *= temp[h] / (nqv * nkv);
    float m = g;
#pragma unroll
    for (int off = 8; off; off >>= 1) m = fmaxf(m, __shfl_xor(m, off, 16));
    float e = __expf(g - m);
    float ssum = e;
#pragma unroll
    for (int off = 8; off; off >>= 1) ssum += __shfl_xor(ssum, off, 16);
    attn[(bz * 8 + h) * 256 + t] = e / ssum;
}

__global__ __launch_bounds__(256) void av_kernel(const float* __restrict__ attn,
                                                 const unsigned short* __restrict__ V, size_t sv,
                                                 unsigned short* __restrict__ Y, size_t sy)
{
    __shared__ __align__(16) float kv[16][260];
    __shared__ __align__(16) float at[16][16];
    int tile = blockIdx.x, h = blockIdx.y, bz = blockIdx.z;
    int n0 = tile * 256, t = threadIdx.x;
    const unsigned short* vb = V + (size_t)bz * sv + (size_t)(h * 16) * HW_;
    at[t >> 4][t & 15] = attn[(size_t)(bz * 8 + h) * 256 + (t & 15) * 16 + (t >> 4)];
#pragma unroll
    for (int i = 0; i < 4; ++i) {
        int e = t + i * 256;        // 1024 ush4 groups: 16 d x 64 nn4
        int d = e >> 6, nn4 = e & 63;
        ush4 v4 = *(const ush4*)(vb + (size_t)d * HW_ + n0 + nn4 * 4);
#pragma unroll
        for (int j = 0; j < 4; ++j) kv[d][nn4 * 4 + j] = bf2f((unsigned short)v4[j]);
    }
    __syncthreads();
    float acc[16];
#pragma unroll
    for (int cc = 0; cc < 16; ++cc) acc[cc] = 0.f;
#pragma unroll
    for (int d = 0; d < 16; ++d) {
        float kvv = kv[d][t];
        float4 a0 = *(const float4*)&at[d][0];
        float4 a1 = *(const float4*)&at[d][4];
        float4 a2 = *(const float4*)&at[d][8];
        float4 a3 = *(const float4*)&at[d][12];
        acc[0]  += a0.x * kvv; acc[1]  += a0.y * kvv; acc[2]  += a0.z * kvv; acc[3]  += a0.w * kvv;
        acc[4]  += a1.x * kvv; acc[5]  += a1.y * kvv; acc[6]  += a1.z * kvv; acc[7]  += a1.w * kvv;
        acc[8]  += a2.x * kvv; acc[9]  += a2.y * kvv; acc[10] += a2.z * kvv; acc[11] += a2.w * kvv;
        acc[12] += a3.x * kvv; acc[13] += a3.y * kvv; acc[14] += a3.z * kvv; acc[15] += a3.w * kvv;
    }
    unsigned short* yb = Y + (size_t)bz * sy + (size_t)(h * 16) * HW_ + n0 + t;
#pragma unroll
    for (int cc = 0; cc < 16; ++cc) yb[(size_t)cc * HW_] = f2bf(acc[cc]);
}

// ---------------------------------------------------------------- 256-pt radix-2 DIT FFT core (32 lanes/row)
__device__ __forceinline__ void fft_stages(float2* row, const float2* tw, int lane)
{
#pragma unroll
    for (int s = 1; s <= 8; ++s) {
        const int half = 1 << (s - 1);
#pragma unroll
        for (int r = 0; r < 4; ++r) {
            int jb = lane + r * 32;
            int j = jb & (half - 1);
            int g = jb >> (s - 1);
            int i1 = (g << s) + j;
            float2 w = tw[j << (8 - s)];
            float2 u = row[i1];
            float2 q = row[i1 + half];
            float2 v = make_float2(q.x * w.x - q.y * w.y, q.x * w.y + q.y * w.x);
            row[i1]        = make_float2(u.x + v.x, u.y + v.y);
            row[i1 + half] = make_float2(u.x - v.x, u.y - v.y);
        }
        __syncthreads();
    }
}

#define PI2_ 6.28318530717958647692f

// bf16 real rows -> transposed packed-bf16 spectrum T[c][k][h]
__global__ __launch_bounds__(256) void rfft_rowsT(const unsigned short* __restrict__ X, size_t sx,
                                                  unsigned* __restrict__ T, size_t st)
{
    __shared__ float2 sd[8][256];
    __shared__ float2 tw[128];
    int t = threadIdx.x;
    int bz = blockIdx.y;
    if (t < 128) { float sn, cs; __sincosf(-PI2_ * (float)t * (1.f / 256.f), &sn, &cs); tw[t] = make_float2(cs, sn); }
    size_t r0 = (size_t)blockIdx.x * 8;
    int c = (int)(r0 >> 8), h0 = (int)(r0 & 255);
    const unsigned short* Xb = X + (size_t)bz * sx;
#pragma unroll
    for (int ii = 0; ii < 2; ++ii) {
        int e = t + ii * 256;            // 512 ush4 groups: 8 rows x 64
        int j = e >> 6, i4 = e & 63;
        ush4 v4 = *(const ush4*)(Xb + (r0 + j) * 256 + i4 * 4);
#pragma unroll
        for (int k2 = 0; k2 < 4; ++k2)
            sd[j][__brev((unsigned)(i4 * 4 + k2)) >> 24] = make_float2(bf2f((unsigned short)v4[k2]), 0.f);
    }
    __syncthreads();
    fft_stages(sd[t >> 5], tw, t & 31);
    unsigned* base = T + (size_t)bz * st + (size_t)c * PLANEF_;
    for (int e = t; e < 8 * 129; e += 256) {
        int j = e & 7, k = e >> 3;
        base[(size_t)k * 256 + h0 + j] = pack2bf(sd[j][k]);
    }
}

// forward complex FFT along h, in-place on packed-bf16 transposed layout
__global__ __launch_bounds__(256) void cfftT_fwd(unsigned* __restrict__ T, size_t st)
{
    __shared__ float2 sd[8][256];
    __shared__ float2 tw[128];
    int t = threadIdx.x;
    int bz = blockIdx.z;
    if (t < 128) { float sn, cs; __sincosf(-PI2_ * (float)t * (1.f / 256.f), &sn, &cs); tw[t] = make_float2(cs, sn); }
    int k0 = blockIdx.x * 8;
    int c = blockIdx.y;
    unsigned* base = T + (size_t)bz * st + (size_t)c * PLANEF_;
    for (int e = t; e < 2048; e += 256) {
        int j = e >> 8, i = e & 255;
        int k = k0 + j;
        float2 v = (k < KF_) ? upk(base[(size_t)k * 256 + i]) : make_float2(0.f, 0.f);
        sd[j][__brev((unsigned)i) >> 24] = v;
    }
    __syncthreads();
    fft_stages(sd[t >> 5], tw, t & 31);
    for (int e = t; e < 2048; e += 256) {
        int j = e >> 8, i = e & 255;
        int k = k0 + j;
        if (k < KF_) base[(size_t)k * 256 + i] = pack2bf(sd[j][i]);
    }
}

// combine(amp,pha bf16) + inverse h-FFT; writes row-major packed-bf16 spectrum S[c][h][k]
__global__ __launch_bounds__(256) void cifft_combine(const unsigned short* __restrict__ amp, size_t sa,
                                                     const unsigned short* __restrict__ pha, size_t sp,
                                                     unsigned* __restrict__ S, size_t ss)
{
    __shared__ float2 sd[8][256];
    __shared__ float2 tw[128];
    int t = threadIdx.x;
    int bz = blockIdx.z;
    if (t < 128) { float sn, cs; __sincosf(PI2_ * (float)t * (1.f / 256.f), &sn, &cs); tw[t] = make_float2(cs, sn); }
    int k0 = blockIdx.x * 8;
    int c = blockIdx.y;
    const unsigned short* ab = amp + (size_t)bz * sa + (size_t)c * PLANEF_;
    const unsigned short* pb = pha + (size_t)bz * sp + (size_t)c * PLANEF_;
    for (int e = t; e < 2048; e += 256) {
        int j = e >> 8, i = e & 255;
        int k = k0 + j;
        float2 v = make_float2(0.f, 0.f);
        if (k < KF_) {
            float a = bf2f(ab[(size_t)k * 256 + i]);
            float p = bf2f(pb[(size_t)k * 256 + i]);
            float sn, cs;
            __sincosf(p, &sn, &cs);
            v = make_float2(a * cs + 2e-8f, a * sn + 1e-8f);
        }
        sd[j][__brev((unsigned)i) >> 24] = v;
    }
    __syncthreads();
    fft_stages(sd[t >> 5], tw, t & 31);
    unsigned* base = S + (size_t)bz * ss + (size_t)c * PLANEF_;
    for (int e = t; e < 2048; e += 256) {
        int j = e & 7, h = e >> 3;
        int k = k0 + j;
        if (k < KF_) {
            float2 o = sd[j][h];
            base[(size_t)h * KF_ + k] = pack2bf(make_float2(o.x * (1.f / 256.f), o.y * (1.f / 256.f)));
        }
    }
}

// row-major packed-bf16 spectrum -> 256 real (Hermitian) -> |.| -> bf16
__global__ __launch_bounds__(256) void irfft_rows8_abs(const unsigned* __restrict__ S, size_t ss,
                                                       unsigned short* __restrict__ Y, size_t sy)
{
    __shared__ float2 sd[8][256];
    __shared__ float2 tw[128];
    int t = threadIdx.x;
    int bz = blockIdx.y;
    if (t < 128) { float sn, cs; __sincosf(PI2_ * (float)t * (1.f / 256.f), &sn, &cs); tw[t] = make_float2(cs, sn); }
    size_t r0 = (size_t)blockIdx.x * 8;
    const unsigned* Sb = S + (size_t)bz * ss;
    for (int e = t; e < 2048; e += 256) {
        int j = e >> 8, i = e & 255;
        const unsigned* row = Sb + (r0 + j) * 129;
        float2 v;
        if (i < 129) v = upk(row[i]);
        else { float2 w2 = upk(row[256 - i]); v = make_float2(w2.x, -w2.y); }
        sd[j][__brev((unsigned)i) >> 24] = v;
    }
    __syncthreads();
    fft_stages(sd[t >> 5], tw, t & 31);
    unsigned short* Yb = Y + (size_t)bz * sy;
    for (int e = t; e < 2048; e += 256) {
        int j = e >> 8, i = e & 255;
        Yb[(r0 + j) * 256 + i] = f2bf(fabsf(sd[j][i].x * (1.f / 256.f)));
    }
}

// ---------------------------------------------------------------- host
extern "C" void kernel_launch(void* const* d_in, const int* in_sizes, int n_in,
                              void* d_out, int out_size, void* d_ws, size_t ws_size,
                              hipStream_t stream)
{
    (void)in_sizes; (void)n_in; (void)out_size;
    const float* ms    = (const float*)d_in[0];
    const float* pan   = (const float*)d_in[1];
    const float* ln1w  = (const float*)d_in[2];
    const float* ln1b  = (const float*)d_in[3];
    const float* ln2w  = (const float*)d_in[4];
    const float* ln2b  = (const float*)d_in[5];
    const float* qkvw  = (const float*)d_in[6];
    const float* dww   = (const float*)d_in[7];
    const float* temp  = (const float*)d_in[8];
    const float* projw = (const float*)d_in[9];
    const float* pre1w = (const float*)d_in[10];
    const float* pre1b = (const float*)d_in[11];
    const float* pre2w = (const float*)d_in[12];
    const float* pre2b = (const float*)d_in[13];
    const float* amp1w = (const float*)d_in[14];
    const float* amp1b = (const float*)d_in[15];
    const float* amp2w = (const float*)d_in[16];
    const float* amp2b = (const float*)d_in[17];
    const float* pha1w = (const float*)d_in[18];
    const float* pha1b = (const float*)d_in[19];
    const float* pha2w = (const float*)d_in[20];
    const float* pha2b = (const float*)d_in[21];
    const float* postw = (const float*)d_in[22];
    const float* postb = (const float*)d_in[23];
    const float* pinw  = (const float*)d_in[24];
    const float* poutw = (const float*)d_in[25];

    const size_t SLOT  = 8454144;    // ushorts per per-batch slot (covers spatial 8388608 & spectrum)
    const size_t CHWu  = 8388608;    // C*HW ushorts
    const size_t CPFu  = 4227072;    // C*PLANEF ushorts
    const size_t SPECu = 4227072;    // C*PLANEF packed complex (unsigned)
    const size_t PARAMU = 344064;    // bf16 weight ushorts
    const size_t PARAMF = 273792;    // f32 param floats

    auto needB = [&](int nb) -> size_t {
        return 2ull * (33554432ull + (size_t)nb * 3ull * SLOT + PARAMU) + 4ull * PARAMF + 64;
    };
    int NB = (ws_size >= needB(4)) ? 4 : ((ws_size >= needB(2)) ? 2 : 1);

    unsigned short* F  = (unsigned short*)d_ws;      // 33554432 ushorts: frefuse bf16 (all batches)
    unsigned short* U0 = F + 33554432;
    unsigned short* U1 = U0 + (size_t)NB * SLOT;
    unsigned short* U2 = U1 + (size_t)NB * SLOT;
    unsigned short* w_qkv   = U2 + (size_t)NB * SLOT;
    unsigned short* w_proj  = w_qkv  + 16384;
    unsigned short* w_pre1  = w_proj + 16384;
    unsigned short* w_pre2  = w_pre1 + 16384;
    unsigned short* w_post  = w_pre2 + 16384;
    unsigned short* w_amp1  = w_post + 16384;   // [128][256]
    unsigned short* w_pha1  = w_amp1 + 32768;
    unsigned short* w_amp2  = w_pha1 + 32768;
    unsigned short* w_pha2  = w_amp2 + 16384;
    unsigned short* w_pin   = w_pha2 + 16384;   // [512][256] folded
    unsigned short* w_pout2 = w_pin  + 131072;  // [2][128][128]
    float* fpar   = (float*)(w_pout2 + 32768);
    float* ksumP  = fpar;
    float* nqsq   = ksumP + 128;     // 512
    float* nksq   = nqsq  + 512;     // 512
    float* attnP  = nksq  + 512;     // 8192
    float* partP  = attnP + 8192;    // 262144
    float* qkv_ws = partP + 262144;
    float* qkv_bb = qkv_ws + 128;
    float* pin_ws = qkv_bb + 128;    // 512
    float* pin_bb = pin_ws + 512;    // 512
    float* pinC   = pin_bb + 512;    // 1024 (float4[256])

    float* xout = (float*)d_out;

    auto CVT = [&](const float* src, unsigned short* dst, int n) {
        tobf16_kernel<<<(n + 255) / 256, 256, 0, stream>>>(src, dst, n);
    };
    foldln_kernel<<<128, 128, 0, stream>>>(qkvw, ln1w, ln1b, w_qkv, qkv_ws, qkv_bb, 128);
    foldln_kernel<<<512, 128, 0, stream>>>(pinw, ln2w, ln2b, w_pin, pin_ws, pin_bb, 256);
    CVT(projw, w_proj, 16384);
    CVT(pre1w, w_pre1, 16384); CVT(pre2w, w_pre2, 16384);
    CVT(postw, w_post, 16384);
    CVT(amp1w, w_amp1, 32768); CVT(pha1w, w_pha1, 32768);
    CVT(amp2w, w_amp2, 16384); CVT(pha2w, w_pha2, 16384);
    poutperm_kernel<<<128, 256, 0, stream>>>(poutw, w_pout2);
    pinc_kernel<<<1, 256, 0, stream>>>(pin_bb, pin_ws, (float4*)pinC);
    ksum_kernel<<<1, 128, 0, stream>>>(dww, ksumP);

    const size_t CHW = (size_t)C_ * HW_;   // floats
    const float* NUL = nullptr;

    for (int b0 = 0; b0 < B_; b0 += NB) {
        const float* msb  = ms  + (size_t)b0 * CHW;
        const float* panb = pan + (size_t)b0 * CHW;
        float* xb = xout + (size_t)b0 * CHW;
        unsigned short* freb = F + (size_t)b0 * CHWu;
        dim3 gz(512, 1, NB);
        dim3 gzf(258, 1, NB);

        // ---- attention ----
        zero2_kernel<<<(NB * 128 + 255) / 256, 256, 0, stream>>>(nqsq, nksq, NB * 128);
        mconv2<0, 1, 0, true><<<gz, 256, 0, stream>>>(
            msb, CHW, w_qkv, 128, nullptr, nullptr, 0, U0, SLOT, HW_, 0, qkv_ws, qkv_bb);
        dwconv2<<<dim3(64, 128, NB), 256, 0, stream>>>(U0, SLOT, dww, ksumP, U1, SLOT, nqsq);   // q
        mconv2<0, 1, 0, true><<<gz, 256, 0, stream>>>(
            panb, CHW, w_qkv, 128, nullptr, nullptr, 0, U0, SLOT, HW_, 0, qkv_ws, qkv_bb);
        dwconv2<<<dim3(64, 128, NB), 256, 0, stream>>>(U0, SLOT, dww, ksumP, U2, SLOT, nksq);   // kv
        gram_kernel<<<dim3(32, 8, NB), 256, 0, stream>>>(U1, SLOT, U2, SLOT, partP);
        softmax_kernel<<<dim3(8, NB), 256, 0, stream>>>(partP, nqsq, nksq, temp, attnP);
        av_kernel<<<dim3(256, 8, NB), 256, 0, stream>>>(attnP, U2, SLOT, U0, SLOT);
        mconv2<1, 0, 0, false><<<gz, 256, 0, stream>>>(
            U0, SLOT, w_proj, 128, nullptr, msb, CHW, xb, CHW, HW_, 0, NUL, NUL);

        // ---- freprocess ----
        mconv2<0, 1, 0, false><<<gz, 256, 0, stream>>>(
            msb, CHW, w_pre1, 128, pre1b, nullptr, 0, U0, SLOT, HW_, 1, NUL, NUL);
        rfft_rowsT<<<dim3(4096, NB), 256, 0, stream>>>(U0, SLOT, (unsigned*)(void*)U1, SPECu);
        cfftT_fwd<<<dim3(17, 128, NB), 256, 0, stream>>>((unsigned*)(void*)U1, SPECu);
        mconv2<0, 1, 0, false><<<gz, 256, 0, stream>>>(
            panb, CHW, w_pre2, 128, pre2b, nullptr, 0, U0, SLOT, HW_, 1, NUL, NUL);
        rfft_rowsT<<<dim3(4096, NB), 256, 0, stream>>>(U0, SLOT, (unsigned*)(void*)U2, SPECu);
        cfftT_fwd<<<dim3(17, 128, NB), 256, 0, stream>>>((unsigned*)(void*)U2, SPECu);
        apconv<<<gzf, 256, 0, stream>>>(
            (const unsigned*)(void*)U1, (const unsigned*)(void*)U2, SPECu,
            w_amp1, w_pha1, amp1b, pha1b, U0, U0 + CPFu, SLOT);
        mconv2<1, 1, 1, false><<<gzf, 256, 0, stream>>>(            // amp = amp2(leaky(AH))
            U0, SLOT, w_amp2, 128, amp2b, nullptr, 0, U1, SLOT, PLANEF_, 0, NUL, NUL);
        mconv2<1, 1, 1, false><<<gzf, 256, 0, stream>>>(            // pha = pha2(leaky(PH))
            U0 + CPFu, SLOT, w_pha2, 128, pha2b, nullptr, 0, U1 + CPFu, SLOT, PLANEF_, 0, NUL, NUL);
        cifft_combine<<<dim3(17, 128, NB), 256, 0, stream>>>(
            U1, SLOT, U1 + CPFu, SLOT, (unsigned*)(void*)U2, SPECu);
        irfft_rows8_abs<<<dim3(4096, NB), 256, 0, stream>>>((unsigned*)(void*)U2, SPECu, U0, SLOT);
        mconv2<1, 1, 0, false><<<gz, 256, 0, stream>>>(
            U0, SLOT, w_post, 128, postb, nullptr, 0, freb, CHWu, HW_, 0, NUL, NUL);
    }

    // ---- FFN (full batch, LN2 + gelu-gate fused) ----
    ffn_mfma5<<<dim3(HW_ / 64, B_), 256, 0, stream>>>(xout, F, w_pin, w_pout2, (const float4*)pinC, xout);
}

// Round 9
// 1797.697 us; speedup vs baseline: 1.3918x; 1.0354x over previous
//
#include <hip/hip_runtime.h>
#include <math.h>

#define B_ 4
#define C_ 128
#define HW_ 65536
#define H__ 256
#define KF_ 129
#define PLANEF_ 33024

typedef __attribute__((ext_vector_type(8))) short short8v;
typedef __attribute__((ext_vector_type(4))) float f32x4;
typedef __attribute__((ext_vector_type(4))) unsigned short ush4;
typedef __attribute__((ext_vector_type(8))) unsigned short ush8;

__device__ __forceinline__ unsigned short f2bf(float f) {
    union { float f; unsigned u; } v; v.f = f;
    return (unsigned short)((v.u + 0x7FFFu + ((v.u >> 16) & 1u)) >> 16);
}
__device__ __forceinline__ float bf2f(unsigned short s) {
    union { unsigned u; float f; } v; v.u = (unsigned)s << 16;
    return v.f;
}
__device__ __forceinline__ unsigned pack2bf(float2 v) {
    return (unsigned)f2bf(v.x) | ((unsigned)f2bf(v.y) << 16);
}
__device__ __forceinline__ float2 upk(unsigned u) {
    return make_float2(bf2f((unsigned short)(u & 0xffff)), bf2f((unsigned short)(u >> 16)));
}
// fast gelu: A&S 7.1.26 erf (|err|<=1.5e-7) with __expf
__device__ __forceinline__ float geluf(float x) {
    float z = 0.70710678118654752f * fabsf(x);
    float t = __fdividef(1.f, fmaf(0.3275911f, z, 1.f));
    float p = fmaf(1.061405429f, t, -1.453152027f);
    p = fmaf(p, t, 1.421413741f);
    p = fmaf(p, t, -0.284496736f);
    p = fmaf(p, t, 0.254829592f);
    p = p * t;
    float erfv = 1.f - p * __expf(-z * z);
    float cdf = (x >= 0.f) ? fmaf(0.5f, erfv, 0.5f) : fmaf(-0.5f, erfv, 0.5f);
    return x * cdf;
}
// fast atan2, poly err ~1e-5 rad
__device__ __forceinline__ float fatan2(float y, float x) {
    float ax = fabsf(x), ay = fabsf(y);
    float mx = fmaxf(ax, ay), mn = fminf(ax, ay);
    float a = __fdividef(mn, fmaxf(mx, 1e-38f));
    float s = a * a;
    float r = fmaf(0.0208351f, s, -0.0851330f);
    r = fmaf(r, s, 0.1801410f);
    r = fmaf(r, s, -0.3302995f);
    r = fmaf(r, s, 0.9998660f);
    r = r * a;
    if (ay > ax) r = 1.57079632679489662f - r;
    if (x < 0.f) r = 3.14159265358979324f - r;
    return copysignf(r, y);
}
// LDS XOR swizzle on byte-offset within row
template<int W>
__device__ __forceinline__ char* swz_ptr(unsigned short (*xs)[W], int px, int cb) {
    return (char*)xs + px * (W * 2) + (cb ^ (((px >> 2) & 7) << 4));
}

// ---------------------------------------------------------------- prep
__global__ __launch_bounds__(256) void tobf16_kernel(const float* __restrict__ src,
                                                     unsigned short* __restrict__ dst, int n)
{
    int i = blockIdx.x * 256 + threadIdx.x;
    if (i < n) dst[i] = f2bf(src[i]);
}

__global__ __launch_bounds__(128) void foldln_kernel(const float* __restrict__ W,
                                                     const float* __restrict__ lnw,
                                                     const float* __restrict__ lnb,
                                                     unsigned short* __restrict__ Wb,
                                                     float* __restrict__ wsum, float* __restrict__ bsum,
                                                     int Cc)
{
    int o = blockIdx.x, t = threadIdx.x;
    float sw = 0.f, sb = 0.f;
    for (int c = t; c < Cc; c += 128) {
        float w = W[(size_t)o * Cc + c];
        float fw = w * lnw[c];
        unsigned short us = f2bf(fw);
        Wb[(size_t)o * Cc + c] = us;
        sw += bf2f(us);
        sb += w * lnb[c];
    }
    __shared__ float r1[128], r2[128];
    r1[t] = sw; r2[t] = sb; __syncthreads();
    for (int st = 64; st; st >>= 1) {
        if (t < st) { r1[t] += r1[t + st]; r2[t] += r2[t + st]; }
        __syncthreads();
    }
    if (!t) { wsum[o] = r1[0]; bsum[o] = r2[0]; }
}

__global__ __launch_bounds__(256) void poutperm_kernel(const float* __restrict__ src,
                                                       unsigned short* __restrict__ dst)
{
    int i = blockIdx.x * 256 + threadIdx.x;   // 32768
    int half = i >> 14, rem = i & 16383, o = rem >> 7, kp = rem & 127;
    int h = (kp >> 5) * 64 + half * 32 + (kp & 31);
    dst[i] = f2bf(src[o * 256 + h]);
}

__global__ void pinc_kernel(const float* __restrict__ bb, const float* __restrict__ ws,
                            float4* __restrict__ pinC)
{
    int i = threadIdx.x;
    if (i < 256) pinC[i] = make_float4(bb[i], ws[i], bb[i + 256], ws[i + 256]);
}

__global__ void ksum_kernel(const float* __restrict__ dw, float* __restrict__ ks)
{
    int c = threadIdx.x;
    if (c < C_) {
        float s = 0.f;
        for (int k = 0; k < 9; ++k) s += dw[c * 9 + k];
        ks[c] = s;
    }
}

__global__ __launch_bounds__(256) void zero2_kernel(float* __restrict__ a, float* __restrict__ b, int n)
{
    int i = blockIdx.x * 256 + threadIdx.x;
    if (i < n) { a[i] = 0.f; b[i] = 0.f; }
}

// ---------------------------------------------------------------- MFMA conv1x1 (CIN=128)
// INBF: input dtype 0=f32 1=bf16. OUTBF: output dtype. PRO==1: leaky(0.1) on staged value.
// LNF: register LN stats + folded-affine epilogue (requires INBF=0). flags&1: +1e-8 after bias.
template<int INBF, int OUTBF, int PRO, bool LNF>
__global__ __launch_bounds__(256, 3) void mconv2(
    const void* __restrict__ Xv, size_t sx,
    const unsigned short* __restrict__ Wb, int wstride,
    const float* __restrict__ bias,
    const float* __restrict__ res, size_t sres,
    void* __restrict__ Yv, size_t sy, int plane, int flags,
    const float* __restrict__ wsum, const float* __restrict__ bsum)
{
    __shared__ unsigned short xs[128][136];
    __shared__ float2 lnred[LNF ? 8 : 1][LNF ? 128 : 1];
    __shared__ float2 lnmi[LNF ? 128 : 1];
    const int t = threadIdx.x;
    const int bz = blockIdx.z;
    const int p0 = blockIdx.x * 128;
    const int lane = t & 63;
    const int wr = t >> 7, wc = (t >> 6) & 1;
    const int lr = lane >> 4, lc = lane & 15;

    if constexpr (INBF == 0) {
        const float* Xb = (const float*)Xv + (size_t)bz * sx;
        const int px4 = t & 31;
        float s0 = 0.f, s1 = 0.f, s2v = 0.f, s3 = 0.f;
        float q0 = 0.f, q1 = 0.f, q2 = 0.f, q3 = 0.f;
#pragma unroll
        for (int g = 0; g < 2; ++g) {
            float4 st[8];
#pragma unroll
            for (int i = 0; i < 8; ++i) {
                int e = t + (g * 8 + i) * 256;           // 4096 items: 128c x 32 px4
                int c = e >> 5;
                st[i] = *(const float4*)(Xb + (size_t)c * plane + p0 + px4 * 4);
            }
#pragma unroll
            for (int i = 0; i < 8; ++i) {
                int e = t + (g * 8 + i) * 256;
                int c = e >> 5;
                float a0 = st[i].x, a1 = st[i].y, a2 = st[i].z, a3 = st[i].w;
                if constexpr (PRO == 1) {
                    a0 = a0 > 0.f ? a0 : 0.1f * a0;
                    a1 = a1 > 0.f ? a1 : 0.1f * a1;
                    a2 = a2 > 0.f ? a2 : 0.1f * a2;
                    a3 = a3 > 0.f ? a3 : 0.1f * a3;
                }
                if constexpr (LNF) {
                    s0 += a0; q0 += a0 * a0;
                    s1 += a1; q1 += a1 * a1;
                    s2v += a2; q2 += a2 * a2;
                    s3 += a3; q3 += a3 * a3;
                }
                *(unsigned short*)swz_ptr(xs, px4 * 4 + 0, 2 * c) = f2bf(a0);
                *(unsigned short*)swz_ptr(xs, px4 * 4 + 1, 2 * c) = f2bf(a1);
                *(unsigned short*)swz_ptr(xs, px4 * 4 + 2, 2 * c) = f2bf(a2);
                *(unsigned short*)swz_ptr(xs, px4 * 4 + 3, 2 * c) = f2bf(a3);
            }
        }
        if constexpr (LNF) {
            lnred[t >> 5][px4 * 4 + 0] = make_float2(s0, q0);
            lnred[t >> 5][px4 * 4 + 1] = make_float2(s1, q1);
            lnred[t >> 5][px4 * 4 + 2] = make_float2(s2v, q2);
            lnred[t >> 5][px4 * 4 + 3] = make_float2(s3, q3);
        }
    } else {
        const unsigned short* Xb = (const unsigned short*)Xv + (size_t)bz * sx;
        ush8 st[8];
#pragma unroll
        for (int i = 0; i < 8; ++i) {
            int e = t + i * 256;                         // 2048 items: 128c x 16 px8
            int c = e >> 4, px8 = e & 15;
            st[i] = *(const ush8*)(Xb + (size_t)c * plane + p0 + px8 * 8);
        }
#pragma unroll
        for (int i = 0; i < 8; ++i) {
            int e = t + i * 256;
            int c = e >> 4, px8 = e & 15;
#pragma unroll
            for (int j = 0; j < 8; ++j) {
                unsigned short us = (unsigned short)st[i][j];
                if constexpr (PRO == 1) {
                    float f = bf2f(us);
                    f = f > 0.f ? f : 0.1f * f;
                    us = f2bf(f);
                }
                *(unsigned short*)swz_ptr(xs, px8 * 8 + j, 2 * c) = us;
            }
        }
    }
    __syncthreads();
    if constexpr (LNF) {
        if (t < 128) {
            float ss = 0.f, qq = 0.f;
#pragma unroll
            for (int j = 0; j < 8; ++j) { float2 a = lnred[j][t]; ss += a.x; qq += a.y; }
            float m = ss * (1.f / 128.f);
            float inv = rsqrtf(qq * (1.f / 128.f) - m * m + 1e-5f);
            lnmi[t] = make_float2(m, inv);
        }
        __syncthreads();
    }

    f32x4 acc[4][4];
#pragma unroll
    for (int mi = 0; mi < 4; ++mi)
#pragma unroll
        for (int ni = 0; ni < 4; ++ni) acc[mi][ni] = (f32x4){0.f, 0.f, 0.f, 0.f};

#pragma unroll
    for (int kk = 0; kk < 128; kk += 32) {
        short8v bfr[4];
#pragma unroll
        for (int ni = 0; ni < 4; ++ni)
            bfr[ni] = *(const short8v*)swz_ptr(xs, wc * 64 + ni * 16 + lc, 2 * (kk + lr * 8));
#pragma unroll
        for (int mi = 0; mi < 4; ++mi) {
            int row = wr * 64 + mi * 16 + lc;
            short8v afr = *(const short8v*)(Wb + (size_t)row * wstride + kk + lr * 8);
#pragma unroll
            for (int ni = 0; ni < 4; ++ni)
                acc[mi][ni] = __builtin_amdgcn_mfma_f32_16x16x32_bf16(afr, bfr[ni], acc[mi][ni], 0, 0, 0);
        }
    }

    float2 mrow[4];
    if constexpr (LNF) {
#pragma unroll
        for (int ni = 0; ni < 4; ++ni) mrow[ni] = lnmi[wc * 64 + ni * 16 + lc];
    }

#pragma unroll
    for (int mi = 0; mi < 4; ++mi) {
        int ob = wr * 64 + mi * 16 + lr * 4;
#pragma unroll
        for (int r = 0; r < 4; ++r) {
            int o = ob + r;
            float bv = 0.f, wso = 0.f;
            if constexpr (LNF) { bv = bsum[o]; wso = wsum[o]; }
            else { if (bias) bv = bias[o]; if (flags & 1) bv += 1e-8f; }
#pragma unroll
            for (int ni = 0; ni < 4; ++ni) {
                int px = wc * 64 + ni * 16 + lc;
                float v;
                if constexpr (LNF) {
                    float m = mrow[ni].x, inv = mrow[ni].y;
                    v = acc[mi][ni][r] * inv + bv - m * inv * wso;
                } else {
                    v = acc[mi][ni][r] + bv;
                }
                if constexpr (OUTBF == 0) {
                    float* Y = (float*)Yv;
                    size_t yi = (size_t)bz * sy + (size_t)o * plane + p0 + px;
                    if (res) v += res[(size_t)bz * sres + (size_t)o * plane + p0 + px];
                    Y[yi] = v;
                } else {
                    unsigned short* Y = (unsigned short*)Yv;
                    Y[(size_t)bz * sy + (size_t)o * plane + p0 + px] = f2bf(v);
                }
            }
        }
    }
}

// ---------------------------------------------------------------- fused amp1+pha1+amp2+pha2 spectral block
// stage A: CIN=256 over two bf16 spectra -> AH/PH accs; stage B: leaky -> LDS -> 2nd GEMM -> amp/pha out.
__global__ __launch_bounds__(256, 2) void apconv2(
    const unsigned* __restrict__ T1, const unsigned* __restrict__ T2, size_t sT,
    const unsigned short* __restrict__ Wa1, const unsigned short* __restrict__ Wp1,  // [128][256]
    const unsigned short* __restrict__ Wa2, const unsigned short* __restrict__ Wp2,  // [128][128]
    const float* __restrict__ ba1, const float* __restrict__ bp1,
    const float* __restrict__ ba2, const float* __restrict__ bp2,
    unsigned short* __restrict__ AMP, unsigned short* __restrict__ PHA, size_t sO)
{
    __shared__ __align__(16) unsigned short buf[2][128][72];   // stage A: xa/xp ; stage B: [128][144]
    const int t = threadIdx.x;
    const int bz = blockIdx.z;
    const int p0 = blockIdx.x * 128;
    const int lane = t & 63;
    const int wr = t >> 7, wc = (t >> 6) & 1;
    const int lr = lane >> 4, lc = lane & 15;
    const int px2 = t & 63;

    typedef unsigned short (*row72)[72];
    typedef unsigned short (*row144)[144];
    row72 xa = (row72)buf[0];
    row72 xp = (row72)buf[1];
    row144 hb = (row144)&buf[0][0][0];

    f32x4 aa[4][4], ap[4][4];
#pragma unroll
    for (int mi = 0; mi < 4; ++mi)
#pragma unroll
        for (int ni = 0; ni < 4; ++ni) { aa[mi][ni] = (f32x4){0.f,0.f,0.f,0.f}; ap[mi][ni] = (f32x4){0.f,0.f,0.f,0.f}; }

    // ---- stage A: amp1/pha1 over both spectra (K=256 in 4 chunks of 64) ----
    for (int ch = 0; ch < 256; ch += 64) {
        const unsigned* Ts = ((ch < 128) ? T1 : T2) + (size_t)bz * sT + (size_t)(ch & 127) * PLANEF_;
#pragma unroll
        for (int g = 0; g < 2; ++g) {
            uint2 st[8];
#pragma unroll
            for (int i = 0; i < 8; ++i) {
                int e = t + (g * 8 + i) * 256;       // 4096 items: 64c x 64 px2 (=128 px)
                int c = e >> 6;
                st[i] = *(const uint2*)(Ts + (size_t)c * PLANEF_ + p0 + px2 * 2);
            }
#pragma unroll
            for (int i = 0; i < 8; ++i) {
                int e = t + (g * 8 + i) * 256;
                int c = e >> 6;
                float2 z0 = upk(st[i].x), z1 = upk(st[i].y);
                float m0 = sqrtf(z0.x * z0.x + z0.y * z0.y);
                float m1 = sqrtf(z1.x * z1.x + z1.y * z1.y);
                float a0 = fatan2(z0.y, z0.x);
                float a1 = fatan2(z1.y, z1.x);
                *(unsigned short*)swz_ptr(xa, px2 * 2 + 0, 2 * c) = f2bf(m0);
                *(unsigned short*)swz_ptr(xa, px2 * 2 + 1, 2 * c) = f2bf(m1);
                *(unsigned short*)swz_ptr(xp, px2 * 2 + 0, 2 * c) = f2bf(a0);
                *(unsigned short*)swz_ptr(xp, px2 * 2 + 1, 2 * c) = f2bf(a1);
            }
        }
        __syncthreads();
#pragma unroll
        for (int kk = 0; kk < 64; kk += 32) {
            short8v bfa[4], bfp[4];
#pragma unroll
            for (int ni = 0; ni < 4; ++ni) {
                bfa[ni] = *(const short8v*)swz_ptr(xa, wc * 64 + ni * 16 + lc, 2 * (kk + lr * 8));
                bfp[ni] = *(const short8v*)swz_ptr(xp, wc * 64 + ni * 16 + lc, 2 * (kk + lr * 8));
            }
#pragma unroll
            for (int mi = 0; mi < 4; ++mi) {
                int row = wr * 64 + mi * 16 + lc;
                short8v afa = *(const short8v*)(Wa1 + (size_t)row * 256 + ch + kk + lr * 8);
                short8v afp = *(const short8v*)(Wp1 + (size_t)row * 256 + ch + kk + lr * 8);
#pragma unroll
                for (int ni = 0; ni < 4; ++ni) {
                    aa[mi][ni] = __builtin_amdgcn_mfma_f32_16x16x32_bf16(afa, bfa[ni], aa[mi][ni], 0, 0, 0);
                    ap[mi][ni] = __builtin_amdgcn_mfma_f32_16x16x32_bf16(afp, bfp[ni], ap[mi][ni], 0, 0, 0);
                }
            }
        }
        __syncthreads();
    }

    // ---- stage B (amp): leaky(AH+b) -> LDS transposed -> GEMM with amp2 -> AMP out ----
#pragma unroll
    for (int mi = 0; mi < 4; ++mi)
#pragma unroll
        for (int r = 0; r < 4; ++r) {
            int o = wr * 64 + mi * 16 + lr * 4 + r;
            float bva = ba1[o];
#pragma unroll
            for (int ni = 0; ni < 4; ++ni) {
                int px = wc * 64 + ni * 16 + lc;
                float v = aa[mi][ni][r] + bva;
                v = v > 0.f ? v : 0.1f * v;
                *(unsigned short*)swz_ptr(hb, px, 2 * o) = f2bf(v);
            }
        }
    __syncthreads();
    {
        f32x4 acc[4][4];
#pragma unroll
        for (int mi = 0; mi < 4; ++mi)
#pragma unroll
            for (int ni = 0; ni < 4; ++ni) acc[mi][ni] = (f32x4){0.f,0.f,0.f,0.f};
#pragma unroll
        for (int kk = 0; kk < 128; kk += 32) {
            short8v bfr[4];
#pragma unroll
            for (int ni = 0; ni < 4; ++ni)
                bfr[ni] = *(const short8v*)swz_ptr(hb, wc * 64 + ni * 16 + lc, 2 * (kk + lr * 8));
#pragma unroll
            for (int mi = 0; mi < 4; ++mi) {
                int row = wr * 64 + mi * 16 + lc;
                short8v afr = *(const short8v*)(Wa2 + (size_t)row * 128 + kk + lr * 8);
#pragma unroll
                for (int ni = 0; ni < 4; ++ni)
                    acc[mi][ni] = __builtin_amdgcn_mfma_f32_16x16x32_bf16(afr, bfr[ni], acc[mi][ni], 0, 0, 0);
            }
        }
#pragma unroll
        for (int mi = 0; mi < 4; ++mi)
#pragma unroll
            for (int r = 0; r < 4; ++r) {
                int o = wr * 64 + mi * 16 + lr * 4 + r;
                float bv = ba2[o];
#pragma unroll
                for (int ni = 0; ni < 4; ++ni) {
                    int px = wc * 64 + ni * 16 + lc;
                    AMP[(size_t)bz * sO + (size_t)o * PLANEF_ + p0 + px] = f2bf(acc[mi][ni][r] + bv);
                }
            }
    }
    __syncthreads();   // all hb reads done before PH overwrite

    // ---- stage B (pha) ----
#pragma unroll
    for (int mi = 0; mi < 4; ++mi)
#pragma unroll
        for (int r = 0; r < 4; ++r) {
            int o = wr * 64 + mi * 16 + lr * 4 + r;
            float bvp = bp1[o];
#pragma unroll
            for (int ni = 0; ni < 4; ++ni) {
                int px = wc * 64 + ni * 16 + lc;
                float v = ap[mi][ni][r] + bvp;
                v = v > 0.f ? v : 0.1f * v;
                *(unsigned short*)swz_ptr(hb, px, 2 * o) = f2bf(v);
            }
        }
    __syncthreads();
    {
        f32x4 acc[4][4];
#pragma unroll
        for (int mi = 0; mi < 4; ++mi)
#pragma unroll
            for (int ni = 0; ni < 4; ++ni) acc[mi][ni] = (f32x4){0.f,0.f,0.f,0.f};
#pragma unroll
        for (int kk = 0; kk < 128; kk += 32) {
            short8v bfr[4];
#pragma unroll
            for (int ni = 0; ni < 4; ++ni)
                bfr[ni] = *(const short8v*)swz_ptr(hb, wc * 64 + ni * 16 + lc, 2 * (kk + lr * 8));
#pragma unroll
            for (int mi = 0; mi < 4; ++mi) {
                int row = wr * 64 + mi * 16 + lc;
                short8v afr = *(const short8v*)(Wp2 + (size_t)row * 128 + kk + lr * 8);
#pragma unroll
                for (int ni = 0; ni < 4; ++ni)
                    acc[mi][ni] = __builtin_amdgcn_mfma_f32_16x16x32_bf16(afr, bfr[ni], acc[mi][ni], 0, 0, 0);
            }
        }
#pragma unroll
        for (int mi = 0; mi < 4; ++mi)
#pragma unroll
            for (int r = 0; r < 4; ++r) {
                int o = wr * 64 + mi * 16 + lr * 4 + r;
                float bv = bp2[o];
#pragma unroll
                for (int ni = 0; ni < 4; ++ni) {
                    int px = wc * 64 + ni * 16 + lc;
                    PHA[(size_t)bz * sO + (size_t)o * PLANEF_ + p0 + px] = f2bf(acc[mi][ni][r] + bv);
                }
            }
    }
}

// ---------------------------------------------------------------- fused MFMA FFN (x f32, fre bf16)
__global__ __launch_bounds__(256, 3) void ffn_mfma5(
    const float* __restrict__ x, const unsigned short* __restrict__ fre,
    const unsigned short* __restrict__ pinb,    // [512][256] folded bf16
    const unsigned short* __restrict__ pout2,   // [2][128][128] permuted bf16
    const float4* __restrict__ pinC,            // [256] (bb1,ws1,bb2,ws2)
    float* __restrict__ out)
{
    __shared__ unsigned short xs[64][264];
    __shared__ unsigned short hs[64][136];
    __shared__ float2 muinv[64];
    float2* sred = (float2*)&hs[0][0];          // overlay: dead until GEMM1 epilogue
    const int b = blockIdx.y;
    const size_t p0 = (size_t)blockIdx.x * 64;
    const int t = threadIdx.x;
    const int wave = t >> 6, lane = t & 63;
    const int lr = lane >> 4, lc = lane & 15;
    const int px4 = t & 15;

    float s0 = 0.f, s1 = 0.f, s2v = 0.f, s3 = 0.f;
    float q0 = 0.f, q1 = 0.f, q2 = 0.f, q3 = 0.f;
    {
        float4 stx[8];
        ush4 stf[8];
#pragma unroll
        for (int i = 0; i < 8; ++i) {
            int e = t + i * 256;                 // 2048 items: 128c x 16 px4
            int c = e >> 4;
            stx[i] = *(const float4*)(x + ((size_t)b * 128 + c) * HW_ + p0 + px4 * 4);
        }
#pragma unroll
        for (int i = 0; i < 8; ++i) {
            int e = t + i * 256;
            int c = e >> 4;
            stf[i] = *(const ush4*)(fre + (size_t)b * 8388608 + (size_t)c * HW_ + p0 + px4 * 4);
        }
#pragma unroll
        for (int i = 0; i < 8; ++i) {
            int e = t + i * 256;
            int c = e >> 4;
            float a0 = stx[i].x, a1 = stx[i].y, a2 = stx[i].z, a3 = stx[i].w;
            s0 += a0; q0 += a0 * a0;
            s1 += a1; q1 += a1 * a1;
            s2v += a2; q2 += a2 * a2;
            s3 += a3; q3 += a3 * a3;
            *(unsigned short*)swz_ptr(xs, px4 * 4 + 0, 2 * c) = f2bf(a0);
            *(unsigned short*)swz_ptr(xs, px4 * 4 + 1, 2 * c) = f2bf(a1);
            *(unsigned short*)swz_ptr(xs, px4 * 4 + 2, 2 * c) = f2bf(a2);
            *(unsigned short*)swz_ptr(xs, px4 * 4 + 3, 2 * c) = f2bf(a3);
        }
#pragma unroll
        for (int i = 0; i < 8; ++i) {
            int e = t + i * 256;
            int c = e >> 4;
            float a0 = bf2f((unsigned short)stf[i][0]);
            float a1 = bf2f((unsigned short)stf[i][1]);
            float a2 = bf2f((unsigned short)stf[i][2]);
            float a3 = bf2f((unsigned short)stf[i][3]);
            s0 += a0; q0 += a0 * a0;
            s1 += a1; q1 += a1 * a1;
            s2v += a2; q2 += a2 * a2;
            s3 += a3; q3 += a3 * a3;
            *(unsigned short*)swz_ptr(xs, px4 * 4 + 0, 2 * (128 + c)) = (unsigned short)stf[i][0];
            *(unsigned short*)swz_ptr(xs, px4 * 4 + 1, 2 * (128 + c)) = (unsigned short)stf[i][1];
            *(unsigned short*)swz_ptr(xs, px4 * 4 + 2, 2 * (128 + c)) = (unsigned short)stf[i][2];
            *(unsigned short*)swz_ptr(xs, px4 * 4 + 3, 2 * (128 + c)) = (unsigned short)stf[i][3];
        }
    }
    sred[(t >> 4) * 64 + px4 * 4 + 0] = make_float2(s0, q0);
    sred[(t >> 4) * 64 + px4 * 4 + 1] = make_float2(s1, q1);
    sred[(t >> 4) * 64 + px4 * 4 + 2] = make_float2(s2v, q2);
    sred[(t >> 4) * 64 + px4 * 4 + 3] = make_float2(s3, q3);
    __syncthreads();
    if (t < 64) {
        float ss = 0.f, qq = 0.f;
#pragma unroll
        for (int j = 0; j < 16; ++j) { float2 a = sred[j * 64 + t]; ss += a.x; qq += a.y; }
        float m = ss * (1.f / 256.f);
        float inv = rsqrtf(qq * (1.f / 256.f) - m * m + 1e-5f);
        muinv[t] = make_float2(m, inv);
    }
    __syncthreads();

    float2 mrow[4];
#pragma unroll
    for (int ni = 0; ni < 4; ++ni) mrow[ni] = muinv[ni * 16 + lc];

    f32x4 oc[2][4];
#pragma unroll
    for (int mi = 0; mi < 2; ++mi)
#pragma unroll
        for (int ni = 0; ni < 4; ++ni) oc[mi][ni] = (f32x4){0.f, 0.f, 0.f, 0.f};

#pragma unroll
    for (int half = 0; half < 2; ++half) {
        f32x4 a1[2][4], a2[2][4];
#pragma unroll
        for (int mi = 0; mi < 2; ++mi)
#pragma unroll
            for (int ni = 0; ni < 4; ++ni) { a1[mi][ni] = (f32x4){0.f,0.f,0.f,0.f}; a2[mi][ni] = (f32x4){0.f,0.f,0.f,0.f}; }

#pragma unroll
        for (int k0 = 0; k0 < 256; k0 += 32) {
            short8v bfr[4];
#pragma unroll
            for (int ni = 0; ni < 4; ++ni)
                bfr[ni] = *(const short8v*)swz_ptr(xs, ni * 16 + lc, 2 * (k0 + lr * 8));
#pragma unroll
            for (int mi = 0; mi < 2; ++mi) {
                int hrow = wave * 64 + half * 32 + mi * 16 + lc;
                short8v af1 = *(const short8v*)(pinb + (size_t)hrow * 256 + k0 + lr * 8);
                short8v af2 = *(const short8v*)(pinb + (size_t)(hrow + 256) * 256 + k0 + lr * 8);
#pragma unroll
                for (int ni = 0; ni < 4; ++ni) {
                    a1[mi][ni] = __builtin_amdgcn_mfma_f32_16x16x32_bf16(af1, bfr[ni], a1[mi][ni], 0, 0, 0);
                    a2[mi][ni] = __builtin_amdgcn_mfma_f32_16x16x32_bf16(af2, bfr[ni], a2[mi][ni], 0, 0, 0);
                }
            }
        }
        __syncthreads();
#pragma unroll
        for (int mi = 0; mi < 2; ++mi)
#pragma unroll
            for (int r = 0; r < 4; ++r) {
                int ho = wave * 64 + half * 32 + mi * 16 + lr * 4 + r;
                float4 bwc = pinC[ho];
                int kp = wave * 32 + mi * 16 + lr * 4 + r;
#pragma unroll
                for (int ni = 0; ni < 4; ++ni) {
                    float m = mrow[ni].x, inv = mrow[ni].y;
                    float v1 = a1[mi][ni][r] * inv + bwc.x - m * inv * bwc.y;
                    float v2 = a2[mi][ni][r] * inv + bwc.z - m * inv * bwc.w;
                    hs[ni * 16 + lc][kp] = f2bf(geluf(v1) * v2);
                }
            }
        __syncthreads();
#pragma unroll
        for (int k0 = 0; k0 < 128; k0 += 32) {
            short8v bfr2[4];
#pragma unroll
            for (int ni = 0; ni < 4; ++ni)
                bfr2[ni] = *(const short8v*)&hs[ni * 16 + lc][k0 + lr * 8];
#pragma unroll
            for (int mi = 0; mi < 2; ++mi) {
                int orow = wave * 32 + mi * 16 + lc;
                short8v af = *(const short8v*)(pout2 + half * 16384 + orow * 128 + k0 + lr * 8);
#pragma unroll
                for (int ni = 0; ni < 4; ++ni)
                    oc[mi][ni] = __builtin_amdgcn_mfma_f32_16x16x32_bf16(af, bfr2[ni], oc[mi][ni], 0, 0, 0);
            }
        }
    }

#pragma unroll
    for (int mi = 0; mi < 2; ++mi)
#pragma unroll
        for (int r = 0; r < 4; ++r) {
            int o = wave * 32 + mi * 16 + lr * 4 + r;
#pragma unroll
            for (int ni = 0; ni < 4; ++ni) {
                size_t yi = ((size_t)b * 128 + o) * HW_ + p0 + ni * 16 + lc;
                out[yi] = oc[mi][ni][r] + x[yi];
            }
        }
}

// ---------------------------------------------------------------- depthwise 3x3 cd-conv (bf16 in/out) + fused sum-of-squares
__global__ __launch_bounds__(256) void dwconv2(const unsigned short* __restrict__ X, size_t sx,
                                               const float* __restrict__ w9,
                                               const float* __restrict__ ksum,
                                               unsigned short* __restrict__ Y, size_t sy,
                                               float* __restrict__ ssq)
{
    int bz = blockIdx.z;
    int c = blockIdx.y;
    int p4 = blockIdx.x * 256 + threadIdx.x;
    int p0 = p4 * 4;
    int i = p0 >> 8, j0 = p0 & 255;
    const unsigned short* xp = X + (size_t)bz * sx + (size_t)c * HW_;
    const float* wc = w9 + c * 9;
    float a[4] = {0.f, 0.f, 0.f, 0.f};
    float ctr[4];
#pragma unroll
    for (int di = -1; di <= 1; ++di) {
        int ii = i + di;
        if (ii < 0 || ii > 255) continue;
        const unsigned short* row = xp + ii * 256;
        ush4 m4 = *(const ush4*)(row + j0);
        float lft = (j0 > 0) ? bf2f(row[j0 - 1]) : 0.f;
        float rgt = (j0 < 252) ? bf2f(row[j0 + 4]) : 0.f;
        float v[6] = {lft, bf2f((unsigned short)m4[0]), bf2f((unsigned short)m4[1]),
                      bf2f((unsigned short)m4[2]), bf2f((unsigned short)m4[3]), rgt};
        if (di == 0) { ctr[0] = v[1]; ctr[1] = v[2]; ctr[2] = v[3]; ctr[3] = v[4]; }
        float w0 = wc[(di + 1) * 3], w1 = wc[(di + 1) * 3 + 1], w2 = wc[(di + 1) * 3 + 2];
#pragma unroll
        for (int k = 0; k < 4; ++k) a[k] += w0 * v[k] + w1 * v[k + 1] + w2 * v[k + 2];
    }
    float km = 0.7f * ksum[c];
    float o0 = a[0] - km * ctr[0], o1 = a[1] - km * ctr[1];
    float o2 = a[2] - km * ctr[2], o3 = a[3] - km * ctr[3];
    ush4 ov;
    ov[0] = f2bf(o0); ov[1] = f2bf(o1); ov[2] = f2bf(o2); ov[3] = f2bf(o3);
    *(ush4*)(Y + (size_t)bz * sy + (size_t)c * HW_ + p0) = ov;

    float q = o0 * o0 + o1 * o1 + o2 * o2 + o3 * o3;
    __shared__ float red[256];
    red[threadIdx.x] = q; __syncthreads();
    for (int st = 128; st; st >>= 1) {
        if (threadIdx.x < st) red[threadIdx.x] += red[threadIdx.x + st];
        __syncthreads();
    }
    if (!threadIdx.x) atomicAdd(&ssq[bz * C_ + c], red[0]);
}

// ---------------------------------------------------------------- attention helpers (bf16 q/k/v)
__global__ __launch_bounds__(256) void gram_kernel(const unsigned short* __restrict__ Q, size_t sq,
                                                   const unsigned short* __restrict__ K, size_t sk,
                                                   float* __restrict__ part)
{
    int sl = blockIdx.x, h = blockIdx.y, bz = blockIdx.z;
    const unsigned short* qb = Q + (size_t)bz * sq + (size_t)(h * 16) * HW_;
    const unsigned short* kb = K + (size_t)bz * sk + (size_t)(h * 16) * HW_;
    __shared__ __align__(16) float qs[16][68];
    __shared__ __align__(16) float ks[16][68];
    int c = threadIdx.x >> 4, d = threadIdx.x & 15;
    float acc = 0.f;
    for (int n0 = sl * 2048; n0 < (sl + 1) * 2048; n0 += 64) {
        {
            int cc = threadIdx.x >> 4, nn4 = threadIdx.x & 15;
            ush4 qv = *(const ush4*)(qb + (size_t)cc * HW_ + n0 + nn4 * 4);
            ush4 kv = *(const ush4*)(kb + (size_t)cc * HW_ + n0 + nn4 * 4);
#pragma unroll
            for (int j = 0; j < 4; ++j) {
                qs[cc][nn4 * 4 + j] = bf2f((unsigned short)qv[j]);
                ks[cc][nn4 * 4 + j] = bf2f((unsigned short)kv[j]);
            }
        }
        __syncthreads();
#pragma unroll
        for (int nn = 0; nn < 64; nn += 4) {
            float4 qv = *(const float4*)&qs[c][nn];
            float4 kv = *(const float4*)&ks[d][nn];
            acc += qv.x * kv.x + qv.y * kv.y + qv.z * kv.z + qv.w * kv.w;
        }
        __syncthreads();
    }
    part[((size_t)(bz * 8 + h) * 32 + sl) * 256 + threadIdx.x] = acc;
}

__global__ __launch_bounds__(256) void softmax_kernel(const float* __restrict__ part,
                                                      const float* __restrict__ nqsq,
                                                      const float* __restrict__ nksq,
                                                      const float* __restrict__ temp,
                                                      float* __restrict__ attn)
{
    int h = blockIdx.x, bz = blockIdx.y;
    int t = threadIdx.x;
    int c = t >> 4, d = t & 15;
    float g = 0.f;
    for (int sl = 0; sl < 32; ++sl) g += part[((size_t)(bz * 8 + h) * 32 + sl) * 256 + t];
    float nqv = fmaxf(sqrtf(nqsq[bz * C_ + h * 16 + c]), 1e-12f);
    float nkv = fmaxf(sqrtf(nksq[bz * C_ + h * 16 + d]), 1e-12f);
    g *= temp[h] / (nqv * nkv);
    float m = g;
#pragma unroll
    for (int off = 8; off; off >>= 1) m = fmaxf(m, __shfl_xor(m, off, 16));
    float e = __expf(g - m);
    float ssum = e;
#pragma unroll
    for (int off = 8; off; off >>= 1) ssum += __shfl_xor(ssum, off, 16);
    attn[(bz * 8 + h) * 256 + t] = e / ssum;
}

__global__ __launch_bounds__(256) void av_kernel(const float* __restrict__ attn,
                                                 const unsigned short* __restrict__ V, size_t sv,
                                                 unsigned short* __restrict__ Y, size_t sy)
{
    __shared__ __align__(16) float kv[16][260];
    __shared__ __align__(16) float at[16][16];
    int tile = blockIdx.x, h = blockIdx.y, bz = blockIdx.z;
    int n0 = tile * 256, t = threadIdx.x;
    const unsigned short* vb = V + (size_t)bz * sv + (size_t)(h * 16) * HW_;
    at[t >> 4][t & 15] = attn[(size_t)(bz * 8 + h) * 256 + (t & 15) * 16 + (t >> 4)];
#pragma unroll
    for (int i = 0; i < 4; ++i) {
        int e = t + i * 256;        // 1024 ush4 groups: 16 d x 64 nn4
        int d = e >> 6, nn4 = e & 63;
        ush4 v4 = *(const ush4*)(vb + (size_t)d * HW_ + n0 + nn4 * 4);
#pragma unroll
        for (int j = 0; j < 4; ++j) kv[d][nn4 * 4 + j] = bf2f((unsigned short)v4[j]);
    }
    __syncthreads();
    float acc[16];
#pragma unroll
    for (int cc = 0; cc < 16; ++cc) acc[cc] = 0.f;
#pragma unroll
    for (int d = 0; d < 16; ++d) {
        float kvv = kv[d][t];
        float4 a0 = *(const float4*)&at[d][0];
        float4 a1 = *(const float4*)&at[d][4];
        float4 a2 = *(const float4*)&at[d][8];
        float4 a3 = *(const float4*)&at[d][12];
        acc[0]  += a0.x * kvv; acc[1]  += a0.y * kvv; acc[2]  += a0.z * kvv; acc[3]  += a0.w * kvv;
        acc[4]  += a1.x * kvv; acc[5]  += a1.y * kvv; acc[6]  += a1.z * kvv; acc[7]  += a1.w * kvv;
        acc[8]  += a2.x * kvv; acc[9]  += a2.y * kvv; acc[10] += a2.z * kvv; acc[11] += a2.w * kvv;
        acc[12] += a3.x * kvv; acc[13] += a3.y * kvv; acc[14] += a3.z * kvv; acc[15] += a3.w * kvv;
    }
    unsigned short* yb = Y + (size_t)bz * sy + (size_t)(h * 16) * HW_ + n0 + t;
#pragma unroll
    for (int cc = 0; cc < 16; ++cc) yb[(size_t)cc * HW_] = f2bf(acc[cc]);
}

// ---------------------------------------------------------------- 256-pt radix-2 DIT FFT core (32 lanes/row)
// Rows are half-wave-private: in-wave LDS ordering replaces per-stage block barriers.
// One block-wide barrier at the end (store loops read rows produced by other waves).
__device__ __forceinline__ void fft_stages(float2* row, const float2* tw, int lane)
{
#pragma unroll
    for (int s = 1; s <= 8; ++s) {
        const int half = 1 << (s - 1);
#pragma unroll
        for (int r = 0; r < 4; ++r) {
            int jb = lane + r * 32;
            int j = jb & (half - 1);
            int g = jb >> (s - 1);
            int i1 = (g << s) + j;
            float2 w = tw[j << (8 - s)];
            float2 u = row[i1];
            float2 q = row[i1 + half];
            float2 v = make_float2(q.x * w.x - q.y * w.y, q.x * w.y + q.y * w.x);
            row[i1]        = make_float2(u.x + v.x, u.y + v.y);
            row[i1 + half] = make_float2(u.x - v.x, u.y - v.y);
        }
        __builtin_amdgcn_wave_barrier();   // compiler fence; HW: same-wave DS ops complete in order
    }
    __syncthreads();
}

#define PI2_ 6.28318530717958647692f

// bf16 real rows -> transposed packed-bf16 spectrum T[c][k][h]
__global__ __launch_bounds__(256) void rfft_rowsT(const unsigned short* __restrict__ X, size_t sx,
                                                  unsigned* __restrict__ T, size_t st)
{
    __shared__ float2 sd[8][256];
    __shared__ float2 tw[128];
    int t = threadIdx.x;
    int bz = blockIdx.y;
    if (t < 128) { float sn, cs; __sincosf(-PI2_ * (float)t * (1.f / 256.f), &sn, &cs); tw[t] = make_float2(cs, sn); }
    size_t r0 = (size_t)blockIdx.x * 8;
    int c = (int)(r0 >> 8), h0 = (int)(r0 & 255);
    const unsigned short* Xb = X + (size_t)bz * sx;
#pragma unroll
    for (int ii = 0; ii < 2; ++ii) {
        int e = t + ii * 256;            // 512 ush4 groups: 8 rows x 64
        int j = e >> 6, i4 = e & 63;
        ush4 v4 = *(const ush4*)(Xb + (r0 + j) * 256 + i4 * 4);
#pragma unroll
        for (int k2 = 0; k2 < 4; ++k2)
            sd[j][__brev((unsigned)(i4 * 4 + k2)) >> 24] = make_float2(bf2f((unsigned short)v4[k2]), 0.f);
    }
    __syncthreads();
    fft_stages(sd[t >> 5], tw, t & 31);
    unsigned* base = T + (size_t)bz * st + (size_t)c * PLANEF_;
    for (int e = t; e < 8 * 129; e += 256) {
        int j = e & 7, k = e >> 3;
        base[(size_t)k * 256 + h0 + j] = pack2bf(sd[j][k]);
    }
}

// forward complex FFT along h, in-place on packed-bf16 transposed layout
__global__ __launch_bounds__(256) void cfftT_fwd(unsigned* __restrict__ T, size_t st)
{
    __shared__ float2 sd[8][256];
    __shared__ float2 tw[128];
    int t = threadIdx.x;
    int bz = blockIdx.z;
    if (t < 128) { float sn, cs; __sincosf(-PI2_ * (float)t * (1.f / 256.f), &sn, &cs); tw[t] = make_float2(cs, sn); }
    int k0 = blockIdx.x * 8;
    int c = blockIdx.y;
    unsigned* base = T + (size_t)bz * st + (size_t)c * PLANEF_;
    for (int e = t; e < 2048; e += 256) {
        int j = e >> 8, i = e & 255;
        int k = k0 + j;
        float2 v = (k < KF_) ? upk(base[(size_t)k * 256 + i]) : make_float2(0.f, 0.f);
        sd[j][__brev((unsigned)i) >> 24] = v;
    }
    __syncthreads();
    fft_stages(sd[t >> 5], tw, t & 31);
    for (int e = t; e < 2048; e += 256) {
        int j = e >> 8, i = e & 255;
        int k = k0 + j;
        if (k < KF_) base[(size_t)k * 256 + i] = pack2bf(sd[j][i]);
    }
}

// combine(amp,pha bf16) + inverse h-FFT; writes row-major packed-bf16 spectrum S[c][h][k]
__global__ __launch_bounds__(256) void cifft_combine(const unsigned short* __restrict__ amp, size_t sa,
                                                     const unsigned short* __restrict__ pha, size_t sp,
                                                     unsigned* __restrict__ S, size_t ss)
{
    __shared__ float2 sd[8][256];
    __shared__ float2 tw[128];
    int t = threadIdx.x;
    int bz = blockIdx.z;
    if (t < 128) { float sn, cs; __sincosf(PI2_ * (float)t * (1.f / 256.f), &sn, &cs); tw[t] = make_float2(cs, sn); }
    int k0 = blockIdx.x * 8;
    int c = blockIdx.y;
    const unsigned short* ab = amp + (size_t)bz * sa + (size_t)c * PLANEF_;
    const unsigned short* pb = pha + (size_t)bz * sp + (size_t)c * PLANEF_;
    for (int e = t; e < 2048; e += 256) {
        int j = e >> 8, i = e & 255;
        int k = k0 + j;
        float2 v = make_float2(0.f, 0.f);
        if (k < KF_) {
            float a = bf2f(ab[(size_t)k * 256 + i]);
            float p = bf2f(pb[(size_t)k * 256 + i]);
            float sn, cs;
            __sincosf(p, &sn, &cs);
            v = make_float2(a * cs + 2e-8f, a * sn + 1e-8f);
        }
        sd[j][__brev((unsigned)i) >> 24] = v;
    }
    __syncthreads();
    fft_stages(sd[t >> 5], tw, t & 31);
    unsigned* base = S + (size_t)bz * ss + (size_t)c * PLANEF_;
    for (int e = t; e < 2048; e += 256) {
        int j = e & 7, h = e >> 3;
        int k = k0 + j;
        if (k < KF_) {
            float2 o = sd[j][h];
            base[(size_t)h * KF_ + k] = pack2bf(make_float2(o.x * (1.f / 256.f), o.y * (1.f / 256.f)));
        }
    }
}

// row-major packed-bf16 spectrum -> 256 real (Hermitian) -> |.| -> bf16
__global__ __launch_bounds__(256) void irfft_rows8_abs(const unsigned* __restrict__ S, size_t ss,
                                                       unsigned short* __restrict__ Y, size_t sy)
{
    __shared__ float2 sd[8][256];
    __shared__ float2 tw[128];
    int t = threadIdx.x;
    int bz = blockIdx.y;
    if (t < 128) { float sn, cs; __sincosf(PI2_ * (float)t * (1.f / 256.f), &sn, &cs); tw[t] = make_float2(cs, sn); }
    size_t r0 = (size_t)blockIdx.x * 8;
    const unsigned* Sb = S + (size_t)bz * ss;
    for (int e = t; e < 2048; e += 256) {
        int j = e >> 8, i = e & 255;
        const unsigned* row = Sb + (r0 + j) * 129;
        float2 v;
        if (i < 129) v = upk(row[i]);
        else { float2 w2 = upk(row[256 - i]); v = make_float2(w2.x, -w2.y); }
        sd[j][__brev((unsigned)i) >> 24] = v;
    }
    __syncthreads();
    fft_stages(sd[t >> 5], tw, t & 31);
    unsigned short* Yb = Y + (size_t)bz * sy;
    for (int e = t; e < 2048; e += 256) {
        int j = e >> 8, i = e & 255;
        Yb[(r0 + j) * 256 + i] = f2bf(fabsf(sd[j][i].x * (1.f / 256.f)));
    }
}

// ---------------------------------------------------------------- host
extern "C" void kernel_launch(void* const* d_in, const int* in_sizes, int n_in,
                              void* d_out, int out_size, void* d_ws, size_t ws_size,
                              hipStream_t stream)
{
    (void)in_sizes; (void)n_in; (void)out_size;
    const float* ms    = (const float*)d_in[0];
    const float* pan   = (const float*)d_in[1];
    const float* ln1w  = (const float*)d_in[2];
    const float* ln1b  = (const float*)d_in[3];
    const float* ln2w  = (const float*)d_in[4];
    const float* ln2b  = (const float*)d_in[5];
    const float* qkvw  = (const float*)d_in[6];
    const float* dww   = (const float*)d_in[7];
    const float* temp  = (const float*)d_in[8];
    const float* projw = (const float*)d_in[9];
    const float* pre1w = (const float*)d_in[10];
    const float* pre1b = (const float*)d_in[11];
    const float* pre2w = (const float*)d_in[12];
    const float* pre2b = (const float*)d_in[13];
    const float* amp1w = (const float*)d_in[14];
    const float* amp1b = (const float*)d_in[15];
    const float* amp2w = (const float*)d_in[16];
    const float* amp2b = (const float*)d_in[17];
    const float* pha1w = (const float*)d_in[18];
    const float* pha1b = (const float*)d_in[19];
    const float* pha2w = (const float*)d_in[20];
    const float* pha2b = (const float*)d_in[21];
    const float* postw = (const float*)d_in[22];
    const float* postb = (const float*)d_in[23];
    const float* pinw  = (const float*)d_in[24];
    const float* poutw = (const float*)d_in[25];

    const size_t SLOT  = 8454144;    // ushorts per per-batch slot
    const size_t CHWu  = 8388608;    // C*HW ushorts
    const size_t CPFu  = 4227072;    // C*PLANEF ushorts
    const size_t SPECu = 4227072;    // C*PLANEF packed complex (unsigned)
    const size_t PARAMU = 344064;    // bf16 weight ushorts
    const size_t PARAMF = 273792;    // f32 param floats

    auto needB = [&](int nb) -> size_t {
        return 2ull * (33554432ull + (size_t)nb * 3ull * SLOT + PARAMU) + 4ull * PARAMF + 64;
    };
    int NB = (ws_size >= needB(4)) ? 4 : ((ws_size >= needB(2)) ? 2 : 1);

    unsigned short* F  = (unsigned short*)d_ws;      // 33554432 ushorts: frefuse bf16 (all batches)
    unsigned short* U0 = F + 33554432;
    unsigned short* U1 = U0 + (size_t)NB * SLOT;
    unsigned short* U2 = U1 + (size_t)NB * SLOT;
    unsigned short* w_qkv   = U2 + (size_t)NB * SLOT;
    unsigned short* w_proj  = w_qkv  + 16384;
    unsigned short* w_pre1  = w_proj + 16384;
    unsigned short* w_pre2  = w_pre1 + 16384;
    unsigned short* w_post  = w_pre2 + 16384;
    unsigned short* w_amp1  = w_post + 16384;   // [128][256]
    unsigned short* w_pha1  = w_amp1 + 32768;
    unsigned short* w_amp2  = w_pha1 + 32768;
    unsigned short* w_pha2  = w_amp2 + 16384;
    unsigned short* w_pin   = w_pha2 + 16384;   // [512][256] folded
    unsigned short* w_pout2 = w_pin  + 131072;  // [2][128][128]
    float* fpar   = (float*)(w_pout2 + 32768);
    float* ksumP  = fpar;
    float* nqsq   = ksumP + 128;     // 512
    float* nksq   = nqsq  + 512;     // 512
    float* attnP  = nksq  + 512;     // 8192
    float* partP  = attnP + 8192;    // 262144
    float* qkv_ws = partP + 262144;
    float* qkv_bb = qkv_ws + 128;
    float* pin_ws = qkv_bb + 128;    // 512
    float* pin_bb = pin_ws + 512;    // 512
    float* pinC   = pin_bb + 512;    // 1024 (float4[256])

    float* xout = (float*)d_out;

    auto CVT = [&](const float* src, unsigned short* dst, int n) {
        tobf16_kernel<<<(n + 255) / 256, 256, 0, stream>>>(src, dst, n);
    };
    foldln_kernel<<<128, 128, 0, stream>>>(qkvw, ln1w, ln1b, w_qkv, qkv_ws, qkv_bb, 128);
    foldln_kernel<<<512, 128, 0, stream>>>(pinw, ln2w, ln2b, w_pin, pin_ws, pin_bb, 256);
    CVT(projw, w_proj, 16384);
    CVT(pre1w, w_pre1, 16384); CVT(pre2w, w_pre2, 16384);
    CVT(postw, w_post, 16384);
    CVT(amp1w, w_amp1, 32768); CVT(pha1w, w_pha1, 32768);
    CVT(amp2w, w_amp2, 16384); CVT(pha2w, w_pha2, 16384);
    poutperm_kernel<<<128, 256, 0, stream>>>(poutw, w_pout2);
    pinc_kernel<<<1, 256, 0, stream>>>(pin_bb, pin_ws, (float4*)pinC);
    ksum_kernel<<<1, 128, 0, stream>>>(dww, ksumP);

    const size_t CHW = (size_t)C_ * HW_;   // floats
    const float* NUL = nullptr;

    for (int b0 = 0; b0 < B_; b0 += NB) {
        const float* msb  = ms  + (size_t)b0 * CHW;
        const float* panb = pan + (size_t)b0 * CHW;
        float* xb = xout + (size_t)b0 * CHW;
        unsigned short* freb = F + (size_t)b0 * CHWu;
        dim3 gz(512, 1, NB);
        dim3 gzf(258, 1, NB);

        // ---- attention ----
        zero2_kernel<<<(NB * 128 + 255) / 256, 256, 0, stream>>>(nqsq, nksq, NB * 128);
        mconv2<0, 1, 0, true><<<gz, 256, 0, stream>>>(
            msb, CHW, w_qkv, 128, nullptr, nullptr, 0, U0, SLOT, HW_, 0, qkv_ws, qkv_bb);
        dwconv2<<<dim3(64, 128, NB), 256, 0, stream>>>(U0, SLOT, dww, ksumP, U1, SLOT, nqsq);   // q
        mconv2<0, 1, 0, true><<<gz, 256, 0, stream>>>(
            panb, CHW, w_qkv, 128, nullptr, nullptr, 0, U0, SLOT, HW_, 0, qkv_ws, qkv_bb);
        dwconv2<<<dim3(64, 128, NB), 256, 0, stream>>>(U0, SLOT, dww, ksumP, U2, SLOT, nksq);   // kv
        gram_kernel<<<dim3(32, 8, NB), 256, 0, stream>>>(U1, SLOT, U2, SLOT, partP);
        softmax_kernel<<<dim3(8, NB), 256, 0, stream>>>(partP, nqsq, nksq, temp, attnP);
        av_kernel<<<dim3(256, 8, NB), 256, 0, stream>>>(attnP, U2, SLOT, U0, SLOT);
        mconv2<1, 0, 0, false><<<gz, 256, 0, stream>>>(
            U0, SLOT, w_proj, 128, nullptr, msb, CHW, xb, CHW, HW_, 0, NUL, NUL);

        // ---- freprocess ----
        mconv2<0, 1, 0, false><<<gz, 256, 0, stream>>>(
            msb, CHW, w_pre1, 128, pre1b, nullptr, 0, U0, SLOT, HW_, 1, NUL, NUL);
        rfft_rowsT<<<dim3(4096, NB), 256, 0, stream>>>(U0, SLOT, (unsigned*)(void*)U1, SPECu);
        cfftT_fwd<<<dim3(17, 128, NB), 256, 0, stream>>>((unsigned*)(void*)U1, SPECu);
        mconv2<0, 1, 0, false><<<gz, 256, 0, stream>>>(
            panb, CHW, w_pre2, 128, pre2b, nullptr, 0, U0, SLOT, HW_, 1, NUL, NUL);
        rfft_rowsT<<<dim3(4096, NB), 256, 0, stream>>>(U0, SLOT, (unsigned*)(void*)U2, SPECu);
        cfftT_fwd<<<dim3(17, 128, NB), 256, 0, stream>>>((unsigned*)(void*)U2, SPECu);
        // fused amp1+pha1 (stage A) + amp2/pha2 (stage B); amp/pha -> U0 slot (spatial dead)
        apconv2<<<gzf, 256, 0, stream>>>(
            (const unsigned*)(void*)U1, (const unsigned*)(void*)U2, SPECu,
            w_amp1, w_pha1, w_amp2, w_pha2, amp1b, pha1b, amp2b, pha2b,
            U0, U0 + CPFu, SLOT);
        cifft_combine<<<dim3(17, 128, NB), 256, 0, stream>>>(
            U0, SLOT, U0 + CPFu, SLOT, (unsigned*)(void*)U2, SPECu);
        irfft_rows8_abs<<<dim3(4096, NB), 256, 0, stream>>>((unsigned*)(void*)U2, SPECu, U0, SLOT);
        mconv2<1, 1, 0, false><<<gz, 256, 0, stream>>>(
            U0, SLOT, w_post, 128, postb, nullptr, 0, freb, CHWu, HW_, 0, NUL, NUL);
    }

    // ---- FFN (full batch, LN2 + gelu-gate fused) ----
    ffn_mfma5<<<dim3(HW_ / 64, B_), 256, 0, stream>>>(xout, F, w_pin, w_pout2, (const float4*)pinC, xout);
}